// Round 1
// baseline (493.391 us; speedup 1.0000x reference)
//
#include <hip/hip_runtime.h>

// Problem constants
#define BB 2
#define LL 2048
#define DMODEL 1024
#define NH 16
#define FDIM 16
#define HDIM 64
#define DFEAT 273            // 1 + 16 + 256
#define CHK 64               // chunk length
#define NCH (LL / CHK)       // 32
#define BHN (BB * NH)        // 32
#define SSZ (DFEAT * HDIM)   // 17472
#define EPSV 1e-12f
#define INV_RRD 0.5f                   // 1/sqrt(sqrt(16))
#define INV_Q 0.17677669529663687f     // 1/(4*sqrt(2))

// workspace layout (float offsets)
#define OFF_Q  ((size_t)0)
#define OFF_K  (OFF_Q + (size_t)BHN * LL * FDIM)        // +1,048,576
#define OFF_V  (OFF_K + (size_t)BHN * LL * FDIM)        // +1,048,576
#define OFF_S  (OFF_V + (size_t)BHN * LL * HDIM)        // +4,194,304
#define OFF_ZK (OFF_S + (size_t)BHN * NCH * SSZ)        // +17,891,328
#define OFF_Y  (OFF_ZK + (size_t)BHN * NCH * DFEAT)     // +279,552
// total floats = OFF_Y + 4,194,304 = 28,656,640  (~114.6 MB)

// ---------------------------------------------------------------------------
// Generic 128x64-tile fp32 GEMM.
// MODE 0: A = x (4096x1024), B = [Wq|Wk|Wv] (N=1536), scatter-store q/k/v into
//         (b,h,l,d) layout inside ws.
// MODE 1: A = y (4096x1024), B = Wo (N=1024), plain row-major store to out.
// ---------------------------------------------------------------------------
template <int MODE>
__global__ __launch_bounds__(256) void gemm_kernel(
    const float* __restrict__ Amat, const float* __restrict__ W0,
    const float* __restrict__ W1, const float* __restrict__ W2,
    float* __restrict__ dst) {
  __shared__ float As[16][128];  // [k][m]
  __shared__ float Bs[16][64];   // [k][n]
  const int tid = threadIdx.x;
  const int bx = blockIdx.x, by = blockIdx.y;
  const int cbase = bx * 64;

  const float* Wsel;
  int ldB, csub;
  if (MODE == 1) {
    Wsel = W0; ldB = DMODEL; csub = cbase;
  } else {
    if (cbase < 256)      { Wsel = W0; ldB = 256;  csub = cbase; }
    else if (cbase < 512) { Wsel = W1; ldB = 256;  csub = cbase - 256; }
    else                  { Wsel = W2; ldB = 1024; csub = cbase - 512; }
  }

  const int tn = tid & 15, tm = tid >> 4;
  const int m0 = by * 128;
  float acc[8][4];
#pragma unroll
  for (int i = 0; i < 8; i++)
#pragma unroll
    for (int j = 0; j < 4; j++) acc[i][j] = 0.f;

  for (int k0 = 0; k0 < DMODEL; k0 += 16) {
    // A tile 128x16 -> As[k][m] (transposed store)
#pragma unroll
    for (int s = 0; s < 2; s++) {
      int lid = tid * 2 + s;
      int am = lid >> 2, akv = (lid & 3) * 4;
      float4 av = *(const float4*)&Amat[(size_t)(m0 + am) * DMODEL + k0 + akv];
      As[akv + 0][am] = av.x;
      As[akv + 1][am] = av.y;
      As[akv + 2][am] = av.z;
      As[akv + 3][am] = av.w;
    }
    // B tile 16x64
    {
      int bk = tid >> 4, bn = (tid & 15) * 4;
      *(float4*)&Bs[bk][bn] =
          *(const float4*)&Wsel[(size_t)(k0 + bk) * ldB + csub + bn];
    }
    __syncthreads();
#pragma unroll
    for (int kk = 0; kk < 16; kk++) {
      float4 a0 = *(const float4*)&As[kk][tm * 8];
      float4 a1 = *(const float4*)&As[kk][tm * 8 + 4];
      float4 b0 = *(const float4*)&Bs[kk][tn * 4];
      float am_[8] = {a0.x, a0.y, a0.z, a0.w, a1.x, a1.y, a1.z, a1.w};
      float bn_[4] = {b0.x, b0.y, b0.z, b0.w};
#pragma unroll
      for (int i = 0; i < 8; i++)
#pragma unroll
        for (int j = 0; j < 4; j++)
          acc[i][j] = fmaf(am_[i], bn_[j], acc[i][j]);
    }
    __syncthreads();
  }

#pragma unroll
  for (int i = 0; i < 8; i++) {
    int r = m0 + tm * 8 + i;
    float4 o = make_float4(acc[i][0], acc[i][1], acc[i][2], acc[i][3]);
    if (MODE == 1) {
      *(float4*)&dst[(size_t)r * DMODEL + cbase + tn * 4] = o;
    } else {
      int bb = r >> 11, l = r & (LL - 1);
      int c = cbase + tn * 4;
      if (c < 256) {  // q: (b,h,l,16)
        int h = c >> 4, f = c & 15;
        *(float4*)&dst[OFF_Q + (((size_t)(bb * NH + h)) * LL + l) * FDIM + f] = o;
      } else if (c < 512) {  // k
        int c2 = c - 256, h = c2 >> 4, f = c2 & 15;
        *(float4*)&dst[OFF_K + (((size_t)(bb * NH + h)) * LL + l) * FDIM + f] = o;
      } else {  // v: (b,h,l,64)
        int c2 = c - 512, h = c2 >> 6, e = c2 & 63;
        *(float4*)&dst[OFF_V + (((size_t)(bb * NH + h)) * LL + l) * HDIM + e] = o;
      }
    }
  }
}

// ---------------------------------------------------------------------------
// Per-chunk state sums: S[d][e] = sum_c kf[c][d]*v[c][e], zk[d] = sum_c kf[c][d]
// kf computed on the fly from k (16 dims). One block per (b,h,chunk).
// Wave w owns feature rows i = w+4m (m=0..3); lane e = tid&63 owns one column.
// ---------------------------------------------------------------------------
__global__ __launch_bounds__(256) void chunk_state_kernel(float* __restrict__ ws) {
  __shared__ float kc[CHK][FDIM];
  __shared__ float vc[CHK][HDIM];
  const int tid = threadIdx.x;
  const int blk = blockIdx.x;
  const int bh = blk / NCH, nc = blk % NCH;
  const float* kg = ws + OFF_K + ((size_t)bh * LL + nc * CHK) * FDIM;
  const float* vg = ws + OFF_V + ((size_t)bh * LL + nc * CHK) * HDIM;

  *(float4*)&((float*)kc)[tid * 4] = *(const float4*)&kg[tid * 4];
#pragma unroll
  for (int s = 0; s < 4; s++) {
    int idx = tid * 4 + s * 1024;
    *(float4*)&((float*)vc)[idx] = *(const float4*)&vg[idx];
  }
  __syncthreads();

  const int w = tid >> 6, e = tid & 63;
  float acc2[4][16];
  float accL[4] = {0.f, 0.f, 0.f, 0.f};
  float acc0 = 0.f;
#pragma unroll
  for (int m = 0; m < 4; m++)
#pragma unroll
    for (int j = 0; j < 16; j++) acc2[m][j] = 0.f;

  for (int c = 0; c < CHK; c++) {
    float kr[16];
#pragma unroll
    for (int u = 0; u < 4; u++) {
      float4 t4 = *(const float4*)&kc[c][u * 4];
      kr[u * 4] = t4.x; kr[u * 4 + 1] = t4.y;
      kr[u * 4 + 2] = t4.z; kr[u * 4 + 3] = t4.w;
    }
    float kq[4];
#pragma unroll
    for (int m = 0; m < 4; m++) kq[m] = kc[c][w + 4 * m];
    float vv = vc[c][e];
    acc0 += vv;
#pragma unroll
    for (int m = 0; m < 4; m++) {
      float kiv = kq[m] * vv;
      accL[m] += kiv;
#pragma unroll
      for (int j = 0; j < 16; j++) acc2[m][j] = fmaf(kr[j], kiv, acc2[m][j]);
    }
  }

  float* S = ws + OFF_S + (size_t)blk * SSZ;
  if (w == 0) S[e] = acc0;  // d = 0 (constant feature)
#pragma unroll
  for (int m = 0; m < 4; m++) {
    int il = w + 4 * m;
    S[(size_t)(1 + il) * HDIM + e] = accL[m] * INV_RRD;
#pragma unroll
    for (int j = 0; j < 16; j++)
      S[(size_t)(17 + il * 16 + j) * HDIM + e] = acc2[m][j] * INV_Q;
  }

  // z sums (lane-parallel over d)
  float* zk = ws + OFF_ZK + (size_t)blk * DFEAT;
  for (int d = tid; d < DFEAT; d += 256) {
    float sum;
    if (d == 0) {
      sum = (float)CHK;
    } else if (d < 17) {
      int i = d - 1;
      sum = 0.f;
      for (int c = 0; c < CHK; c++) sum += kc[c][i];
      sum *= INV_RRD;
    } else {
      int d2 = d - 17, i = d2 >> 4, j = d2 & 15;
      sum = 0.f;
      for (int c = 0; c < CHK; c++) sum += kc[c][i] * kc[c][j];
      sum *= INV_Q;
    }
    zk[d] = sum;
  }
}

// ---------------------------------------------------------------------------
// Exclusive prefix scan over the chunk axis for S and zk (per (b,h)).
// ---------------------------------------------------------------------------
__global__ __launch_bounds__(256) void scan_kernel(float* __restrict__ ws) {
  const int bh = blockIdx.y;
  const int E = blockIdx.x * 256 + threadIdx.x;
  if (E < SSZ) {
    float* base = ws + OFF_S + (size_t)bh * NCH * SSZ + E;
    float run = 0.f;
    for (int nc = 0; nc < NCH; nc++) {
      float v = base[(size_t)nc * SSZ];
      base[(size_t)nc * SSZ] = run;
      run += v;
    }
  } else if (E < SSZ + DFEAT) {
    int E2 = E - SSZ;
    float* base = ws + OFF_ZK + (size_t)bh * NCH * DFEAT + E2;
    float run = 0.f;
    for (int nc = 0; nc < NCH; nc++) {
      float v = base[nc * DFEAT];
      base[nc * DFEAT] = run;
      run += v;
    }
  }
}

// ---------------------------------------------------------------------------
// Per-chunk output: y = (qf @ S_prefix + tril(f(QK^T)) @ V) / denom.
// f(s) = 1 + s + s^2/2 with s = (q.k)/4  (== phi(q).phi(k), exactly).
// denom = qf.z_prefix + rowsum(tril(f(QK^T))).
// One block (256 thr) per (b,h,chunk). Thread tile: 4 rows x 4 cols.
// ---------------------------------------------------------------------------
__global__ __launch_bounds__(256) void chunk_out_kernel(float* __restrict__ ws) {
  __shared__ float qc[CHK][17];   // +1 pad (17 floats) to kill stride-16 conflicts
  __shared__ float kc[CHK][17];
  __shared__ float vc[CHK][HDIM];
  __shared__ float qfT[64][64];   // [dd][c]
  __shared__ float SpT[64][64];   // [dd][e]; reused as A[cp][ci] in intra phase
  __shared__ float zpT[64];
  __shared__ float zbuf[CHK];

  const int tid = threadIdx.x;
  const int blk = blockIdx.x;
  const int bh = blk / NCH, nc = blk % NCH;
  const int bb = bh >> 4, h = bh & 15;

  const float* qg = ws + OFF_Q + ((size_t)bh * LL + nc * CHK) * FDIM;
  const float* kg = ws + OFF_K + ((size_t)bh * LL + nc * CHK) * FDIM;
  const float* vg = ws + OFF_V + ((size_t)bh * LL + nc * CHK) * HDIM;
  const float* Sp = ws + OFF_S + (size_t)blk * SSZ;
  const float* zp = ws + OFF_ZK + (size_t)blk * DFEAT;

  {
    int c = tid >> 2, u = (tid & 3) * 4;
    float4 t4 = *(const float4*)&qg[c * FDIM + u];
    qc[c][u] = t4.x; qc[c][u + 1] = t4.y; qc[c][u + 2] = t4.z; qc[c][u + 3] = t4.w;
    float4 s4 = *(const float4*)&kg[c * FDIM + u];
    kc[c][u] = s4.x; kc[c][u + 1] = s4.y; kc[c][u + 2] = s4.z; kc[c][u + 3] = s4.w;
  }
#pragma unroll
  for (int s = 0; s < 4; s++) {
    int idx = tid * 4 + s * 1024;
    *(float4*)&((float*)vc)[idx] = *(const float4*)&vg[idx];
  }
  __syncthreads();

  const int tc = tid & 15, te = tid >> 4;
  float acc[4][4];
#pragma unroll
  for (int i = 0; i < 4; i++)
#pragma unroll
    for (int j = 0; j < 4; j++) acc[i][j] = 0.f;
  float zacc = 0.f;

  // ---- inter-chunk: y += qf @ Sp, z += qf . zp  (d tiled by 64, 5 tiles)
  for (int t5 = 0; t5 < 5; t5++) {
    const int d0 = t5 * 64;
#pragma unroll
    for (int u = 0; u < 16; u++) {
      int idx = tid + u * 256;
      int dd = idx >> 6, c = idx & 63;  // dd wave-uniform
      int d = d0 + dd;
      float val;
      if (d >= DFEAT) val = 0.f;
      else if (d == 0) val = 1.f;
      else if (d < 17) val = qc[c][d - 1] * INV_RRD;
      else { int d2 = d - 17; val = qc[c][d2 >> 4] * qc[c][d2 & 15] * INV_Q; }
      qfT[dd][c] = val;
    }
#pragma unroll
    for (int u = 0; u < 4; u++) {
      int idx = tid + u * 256;  // float4 index
      int dd = idx >> 4, ev = (idx & 15) * 4;
      int d = d0 + dd;
      float4 sv;
      if (d < DFEAT) sv = *(const float4*)&Sp[(size_t)d * HDIM + ev];
      else sv = make_float4(0.f, 0.f, 0.f, 0.f);
      *(float4*)&SpT[dd][ev] = sv;
    }
    if (tid < 64) {
      int d = d0 + tid;
      zpT[tid] = (d < DFEAT) ? zp[d] : 0.f;
    }
    __syncthreads();
#pragma unroll 8
    for (int dd = 0; dd < 64; dd++) {
      float4 a4 = *(const float4*)&qfT[dd][tc * 4];
      float4 b4 = *(const float4*)&SpT[dd][te * 4];
      float aa[4] = {a4.x, a4.y, a4.z, a4.w};
      float bv[4] = {b4.x, b4.y, b4.z, b4.w};
#pragma unroll
      for (int i = 0; i < 4; i++)
#pragma unroll
        for (int j = 0; j < 4; j++) acc[i][j] = fmaf(aa[i], bv[j], acc[i][j]);
    }
    if (tid < 64) {
#pragma unroll 8
      for (int dd = 0; dd < 64; dd++) zacc = fmaf(qfT[dd][tid], zpT[dd], zacc);
    }
    __syncthreads();
  }

  // ---- intra-chunk: A[ci][cp] = (cp<=ci) ? 1+s+s^2/2 : 0, stored as SpT[cp][ci]
  {
    float sdot[4][4];
#pragma unroll
    for (int i = 0; i < 4; i++)
#pragma unroll
      for (int p = 0; p < 4; p++) sdot[i][p] = 0.f;
#pragma unroll
    for (int kk = 0; kk < 16; kk++) {
      float qv[4], kv[4];
#pragma unroll
      for (int i = 0; i < 4; i++) qv[i] = qc[tc * 4 + i][kk];
#pragma unroll
      for (int p = 0; p < 4; p++) kv[p] = kc[te * 4 + p][kk];
#pragma unroll
      for (int i = 0; i < 4; i++)
#pragma unroll
        for (int p = 0; p < 4; p++) sdot[i][p] = fmaf(qv[i], kv[p], sdot[i][p]);
    }
#pragma unroll
    for (int i = 0; i < 4; i++)
#pragma unroll
      for (int p = 0; p < 4; p++) {
        int ci = tc * 4 + i, cp = te * 4 + p;
        float s = sdot[i][p] * 0.25f;  // (q.k)/sqrt(16)
        float f = 1.f + s + 0.5f * s * s;
        SpT[cp][ci] = (cp <= ci) ? f : 0.f;
      }
  }
  __syncthreads();

  // y += A @ V
#pragma unroll 8
  for (int cc = 0; cc < 64; cc++) {
    float4 a4 = *(const float4*)&SpT[cc][tc * 4];
    float4 b4 = *(const float4*)&vc[cc][te * 4];
    float aa[4] = {a4.x, a4.y, a4.z, a4.w};
    float bv[4] = {b4.x, b4.y, b4.z, b4.w};
#pragma unroll
    for (int i = 0; i < 4; i++)
#pragma unroll
      for (int j = 0; j < 4; j++) acc[i][j] = fmaf(aa[i], bv[j], acc[i][j]);
  }
  // denominator: z_intra[ci] = sum_cp A[cp][ci]
  if (tid < 64) {
    float zs = zacc;
#pragma unroll 8
    for (int cc = 0; cc < 64; cc++) zs += SpT[cc][tid];
    zbuf[tid] = zs;
  }
  __syncthreads();

  float* y = ws + OFF_Y;
#pragma unroll
  for (int i = 0; i < 4; i++) {
    int c = tc * 4 + i;
    float sc = 1.f / (zbuf[c] + EPSV);
    int p = nc * CHK + c;
    float4 o = make_float4(acc[i][0] * sc, acc[i][1] * sc, acc[i][2] * sc,
                           acc[i][3] * sc);
    *(float4*)&y[((size_t)bb * LL + p) * DMODEL + h * HDIM + te * 4] = o;
  }
}

// ---------------------------------------------------------------------------
extern "C" void kernel_launch(void* const* d_in, const int* in_sizes, int n_in,
                              void* d_out, int out_size, void* d_ws,
                              size_t ws_size, hipStream_t stream) {
  (void)in_sizes; (void)n_in; (void)out_size; (void)ws_size;
  const float* x  = (const float*)d_in[0];
  const float* Wq = (const float*)d_in[1];
  const float* Wk = (const float*)d_in[2];
  const float* Wv = (const float*)d_in[3];
  const float* Wo = (const float*)d_in[4];
  float* ws = (float*)d_ws;
  float* out = (float*)d_out;

  // 1) fused q/k/v projection: (4096x1024) @ (1024x1536)
  gemm_kernel<0><<<dim3(24, 32), 256, 0, stream>>>(x, Wq, Wk, Wv, ws);
  // 2) per-chunk states
  chunk_state_kernel<<<dim3(BHN * NCH), 256, 0, stream>>>(ws);
  // 3) exclusive prefix scan over chunks
  scan_kernel<<<dim3(70, BHN), 256, 0, stream>>>(ws);
  // 4) inter + intra + normalize -> y
  chunk_out_kernel<<<dim3(BHN * NCH), 256, 0, stream>>>(ws);
  // 5) out = y @ Wo
  gemm_kernel<1><<<dim3(16, 32), 256, 0, stream>>>(ws + OFF_Y, Wo, nullptr,
                                                   nullptr, out);
}

// Round 2
// 342.218 us; speedup vs baseline: 1.4417x; 1.4417x over previous
//
#include <hip/hip_runtime.h>

// Problem constants
#define BB 2
#define LL 2048
#define DMODEL 1024
#define NH 16
#define FDIM 16
#define HDIM 64
#define DFEAT 273            // 1 + 16 + 256
#define CHK 64               // chunk length
#define NCH (LL / CHK)       // 32
#define BHN (BB * NH)        // 32
#define SSZ (DFEAT * HDIM)   // 17472
#define EPSV 1e-12f
#define INV_RRD 0.5f                   // 1/sqrt(sqrt(16))
#define INV_Q 0.17677669529663687f     // 1/(4*sqrt(2))

// workspace layout (float offsets)
#define OFF_Q  ((size_t)0)
#define OFF_K  (OFF_Q + (size_t)BHN * LL * FDIM)        // +1,048,576
#define OFF_V  (OFF_K + (size_t)BHN * LL * FDIM)        // +1,048,576
#define OFF_S  (OFF_V + (size_t)BHN * LL * HDIM)        // +4,194,304
#define OFF_ZK (OFF_S + (size_t)BHN * NCH * SSZ)        // +17,891,328
#define OFF_Y  (OFF_ZK + (size_t)BHN * NCH * DFEAT)     // +279,552
// total floats = OFF_Y + 4,194,304 = 28,656,640  (~114.6 MB)
// Overlays (no extra ws):
//   BThi/BTlo (qkv^T bf16 splits, 1536x1024 each) live in OFF_S region
//     (dead until chunk_state runs, which is after gemm<0>).
//   WoThi/WoTlo (1024x1024 each) live in OFF_Q / OFF_K regions
//     (dead after chunk_out; written just before gemm<1>).

typedef __attribute__((ext_vector_type(8))) short s16x8;   // 8 bf16
typedef __attribute__((ext_vector_type(4))) float f32x4;

// bf16 split: a = hi + lo (both bf16, RNE-ish via +0x8000 trick)
__device__ inline void bsplit(float a, short& h, short& l) {
  unsigned int u = __float_as_uint(a);
  unsigned int hu = (u + 0x8000u) >> 16;
  float hf = __uint_as_float(hu << 16);
  float r = a - hf;
  unsigned int ru = __float_as_uint(r);
  h = (short)hu;
  l = (short)((ru + 0x8000u) >> 16);
}

// ---------------------------------------------------------------------------
// Transpose + bf16-split of [Wq|Wk|Wv] (K=1024 rows) into BT[n][k] hi/lo.
// Output rows: n<256 -> Wq col n ; n<512 -> Wk ; else Wv.
// ---------------------------------------------------------------------------
__global__ __launch_bounds__(256) void tsplit_qkv_kernel(
    const float* __restrict__ Wq, const float* __restrict__ Wk,
    const float* __restrict__ Wv, short* __restrict__ dhi,
    short* __restrict__ dlo) {
  __shared__ float tile[32][33];
  const int k0 = blockIdx.x * 32, n0 = blockIdx.y * 32;
  const float* src; int nc, c0;
  if (n0 < 256)      { src = Wq; nc = 256;  c0 = n0; }
  else if (n0 < 512) { src = Wk; nc = 256;  c0 = n0 - 256; }
  else               { src = Wv; nc = 1024; c0 = n0 - 512; }
  const int t = threadIdx.x;
  {
    int kk = t >> 3, c4 = (t & 7) * 4;
    float4 v = *(const float4*)&src[(size_t)(k0 + kk) * nc + c0 + c4];
    tile[kk][c4] = v.x; tile[kk][c4 + 1] = v.y;
    tile[kk][c4 + 2] = v.z; tile[kk][c4 + 3] = v.w;
  }
  __syncthreads();
  int cc = t >> 3, k4 = (t & 7) * 4;
  short4 h4, l4;
  bsplit(tile[k4 + 0][cc], h4.x, l4.x);
  bsplit(tile[k4 + 1][cc], h4.y, l4.y);
  bsplit(tile[k4 + 2][cc], h4.z, l4.z);
  bsplit(tile[k4 + 3][cc], h4.w, l4.w);
  size_t o = (size_t)(n0 + cc) * 1024 + k0 + k4;
  *(short4*)&dhi[o] = h4;
  *(short4*)&dlo[o] = l4;
}

// Same, single source (Wo, 1024 cols)
__global__ __launch_bounds__(256) void tsplit_wo_kernel(
    const float* __restrict__ Wo, short* __restrict__ dhi,
    short* __restrict__ dlo) {
  __shared__ float tile[32][33];
  const int k0 = blockIdx.x * 32, n0 = blockIdx.y * 32;
  const int t = threadIdx.x;
  {
    int kk = t >> 3, c4 = (t & 7) * 4;
    float4 v = *(const float4*)&Wo[(size_t)(k0 + kk) * 1024 + n0 + c4];
    tile[kk][c4] = v.x; tile[kk][c4 + 1] = v.y;
    tile[kk][c4 + 2] = v.z; tile[kk][c4 + 3] = v.w;
  }
  __syncthreads();
  int cc = t >> 3, k4 = (t & 7) * 4;
  short4 h4, l4;
  bsplit(tile[k4 + 0][cc], h4.x, l4.x);
  bsplit(tile[k4 + 1][cc], h4.y, l4.y);
  bsplit(tile[k4 + 2][cc], h4.z, l4.z);
  bsplit(tile[k4 + 3][cc], h4.w, l4.w);
  size_t o = (size_t)(n0 + cc) * 1024 + k0 + k4;
  *(short4*)&dhi[o] = h4;
  *(short4*)&dlo[o] = l4;
}

// ---------------------------------------------------------------------------
// Split-precision bf16 MFMA GEMM: C[m][n] = sum_k A[m][k]*BT[n][k], fp32 A,
// bf16 hi/lo BT. 128x128 tile, 4 waves (2x2), BK=32, mfma_f32_16x16x32_bf16,
// 3 MFMAs per fragment (hh, hl, lh) => fp32-equivalent accuracy.
// MODE 0: A = x, scatter-store q/k/v into ws. MODE 1: A = y, store to out.
// ---------------------------------------------------------------------------
#define LDP 40  // padded LDS row stride in bf16 elems (80B: 16-rows x 4-slots -> 2-way)

template <int MODE>
__global__ __launch_bounds__(256, 2) void mfma_gemm_kernel(
    const float* __restrict__ A, const short* __restrict__ BThi,
    const short* __restrict__ BTlo, float* __restrict__ dst) {
  __shared__ short lAh[128 * LDP];
  __shared__ short lAl[128 * LDP];
  __shared__ short lBh[128 * LDP];
  __shared__ short lBl[128 * LDP];

  const int t = threadIdx.x;
  const int m0 = blockIdx.y * 128, n0 = blockIdx.x * 128;

  // staging assignment: wave w stages rows [w*16, w*16+16) and +64; lane&15 =
  // row in group, lane>>4 = 16B slot. (16 rows x 4 slots per instr -> 2-way.)
  const int sw = t >> 6, sl = t & 63;
  const int sr = (sw << 4) + (sl & 15);  // 0..63
  const int ss = sl >> 4;                // 0..3
  const float* aptr = A + (size_t)(m0 + sr) * 1024 + ss * 8;
  const short* bhp = BThi + (size_t)(n0 + sr) * 1024 + ss * 8;
  const short* blp = BTlo + (size_t)(n0 + sr) * 1024 + ss * 8;
  const int w0 = sr * LDP + ss * 8;          // lds elem offset, pass 0
  const int w1 = (sr + 64) * LDP + ss * 8;   // pass 1

  // compute assignment
  const int lane = t & 63;
  const int wv = t >> 6, wr = wv >> 1, wc = wv & 1;
  const int fr = lane & 15, ks = lane >> 4;
  const int aoffs = (wr * 64 + fr) * LDP + ks * 8;
  const int boffs = (wc * 64 + fr) * LDP + ks * 8;

  f32x4 acc[4][4];
#pragma unroll
  for (int i = 0; i < 4; i++)
#pragma unroll
    for (int j = 0; j < 4; j++) acc[i][j] = (f32x4){0.f, 0.f, 0.f, 0.f};

  for (int k0 = 0; k0 < 1024; k0 += 32) {
    // global loads (issue early)
    float4 a00 = *(const float4*)(aptr + k0);
    float4 a01 = *(const float4*)(aptr + k0 + 4);
    float4 a10 = *(const float4*)(aptr + k0 + 65536);
    float4 a11 = *(const float4*)(aptr + k0 + 65536 + 4);
    s16x8 bh0 = *(const s16x8*)(bhp + k0);
    s16x8 bh1 = *(const s16x8*)(bhp + k0 + 65536);
    s16x8 bl0 = *(const s16x8*)(blp + k0);
    s16x8 bl1 = *(const s16x8*)(blp + k0 + 65536);

    // convert A to hi/lo bf16
    s16x8 h0, l0, h1, l1;
    {
      float v0[8] = {a00.x, a00.y, a00.z, a00.w, a01.x, a01.y, a01.z, a01.w};
      float v1[8] = {a10.x, a10.y, a10.z, a10.w, a11.x, a11.y, a11.z, a11.w};
#pragma unroll
      for (int i = 0; i < 8; i++) {
        short hh, ll;
        bsplit(v0[i], hh, ll); h0[i] = hh; l0[i] = ll;
        bsplit(v1[i], hh, ll); h1[i] = hh; l1[i] = ll;
      }
    }
    __syncthreads();  // previous iteration's reads complete
    *(s16x8*)&lAh[w0] = h0;  *(s16x8*)&lAl[w0] = l0;
    *(s16x8*)&lAh[w1] = h1;  *(s16x8*)&lAl[w1] = l1;
    *(s16x8*)&lBh[w0] = bh0; *(s16x8*)&lBl[w0] = bl0;
    *(s16x8*)&lBh[w1] = bh1; *(s16x8*)&lBl[w1] = bl1;
    __syncthreads();  // tile ready

    s16x8 ah[4], al[4], bh[4], bl[4];
#pragma unroll
    for (int i = 0; i < 4; i++) {
      ah[i] = *(const s16x8*)&lAh[aoffs + i * 16 * LDP];
      al[i] = *(const s16x8*)&lAl[aoffs + i * 16 * LDP];
      bh[i] = *(const s16x8*)&lBh[boffs + i * 16 * LDP];
      bl[i] = *(const s16x8*)&lBl[boffs + i * 16 * LDP];
    }
#pragma unroll
    for (int mi = 0; mi < 4; mi++)
#pragma unroll
      for (int ni = 0; ni < 4; ni++) {
        acc[mi][ni] = __builtin_amdgcn_mfma_f32_16x16x32_bf16(
            ah[mi], bh[ni], acc[mi][ni], 0, 0, 0);
        acc[mi][ni] = __builtin_amdgcn_mfma_f32_16x16x32_bf16(
            ah[mi], bl[ni], acc[mi][ni], 0, 0, 0);
        acc[mi][ni] = __builtin_amdgcn_mfma_f32_16x16x32_bf16(
            al[mi], bh[ni], acc[mi][ni], 0, 0, 0);
      }
  }

  // epilogue: C/D frag mapping col = lane&15 (=fr), row = (lane>>4)*4 + r
#pragma unroll
  for (int mi = 0; mi < 4; mi++) {
    const int rmb = m0 + wr * 64 + mi * 16 + ks * 4;
#pragma unroll
    for (int ni = 0; ni < 4; ni++) {
      const int cn = n0 + wc * 64 + ni * 16 + fr;
      if (MODE == 1) {
#pragma unroll
        for (int r = 0; r < 4; r++)
          dst[(size_t)(rmb + r) * 1024 + cn] = acc[mi][ni][r];
      } else {
        if (cn < 256) {  // q
          int h = cn >> 4, f = cn & 15;
#pragma unroll
          for (int r = 0; r < 4; r++) {
            int rm = rmb + r, b = rm >> 11, l = rm & (LL - 1);
            dst[OFF_Q + (((size_t)(b * NH + h)) * LL + l) * FDIM + f] =
                acc[mi][ni][r];
          }
        } else if (cn < 512) {  // k
          int c2 = cn - 256, h = c2 >> 4, f = c2 & 15;
#pragma unroll
          for (int r = 0; r < 4; r++) {
            int rm = rmb + r, b = rm >> 11, l = rm & (LL - 1);
            dst[OFF_K + (((size_t)(b * NH + h)) * LL + l) * FDIM + f] =
                acc[mi][ni][r];
          }
        } else {  // v
          int c2 = cn - 512, h = c2 >> 6, e = c2 & 63;
#pragma unroll
          for (int r = 0; r < 4; r++) {
            int rm = rmb + r, b = rm >> 11, l = rm & (LL - 1);
            dst[OFF_V + (((size_t)(b * NH + h)) * LL + l) * HDIM + e] =
                acc[mi][ni][r];
          }
        }
      }
    }
  }
}

// ---------------------------------------------------------------------------
// Per-chunk state sums: S[d][e] = sum_c kf[c][d]*v[c][e], zk[d] = sum_c kf[c][d]
// ---------------------------------------------------------------------------
__global__ __launch_bounds__(256) void chunk_state_kernel(float* __restrict__ ws) {
  __shared__ float kc[CHK][FDIM];
  __shared__ float vc[CHK][HDIM];
  const int tid = threadIdx.x;
  const int blk = blockIdx.x;
  const int bh = blk / NCH, nc = blk % NCH;
  const float* kg = ws + OFF_K + ((size_t)bh * LL + nc * CHK) * FDIM;
  const float* vg = ws + OFF_V + ((size_t)bh * LL + nc * CHK) * HDIM;

  *(float4*)&((float*)kc)[tid * 4] = *(const float4*)&kg[tid * 4];
#pragma unroll
  for (int s = 0; s < 4; s++) {
    int idx = tid * 4 + s * 1024;
    *(float4*)&((float*)vc)[idx] = *(const float4*)&vg[idx];
  }
  __syncthreads();

  const int w = tid >> 6, e = tid & 63;
  float acc2[4][16];
  float accL[4] = {0.f, 0.f, 0.f, 0.f};
  float acc0 = 0.f;
#pragma unroll
  for (int m = 0; m < 4; m++)
#pragma unroll
    for (int j = 0; j < 16; j++) acc2[m][j] = 0.f;

  for (int c = 0; c < CHK; c++) {
    float kr[16];
#pragma unroll
    for (int u = 0; u < 4; u++) {
      float4 t4 = *(const float4*)&kc[c][u * 4];
      kr[u * 4] = t4.x; kr[u * 4 + 1] = t4.y;
      kr[u * 4 + 2] = t4.z; kr[u * 4 + 3] = t4.w;
    }
    float kq[4];
#pragma unroll
    for (int m = 0; m < 4; m++) kq[m] = kc[c][w + 4 * m];
    float vv = vc[c][e];
    acc0 += vv;
#pragma unroll
    for (int m = 0; m < 4; m++) {
      float kiv = kq[m] * vv;
      accL[m] += kiv;
#pragma unroll
      for (int j = 0; j < 16; j++) acc2[m][j] = fmaf(kr[j], kiv, acc2[m][j]);
    }
  }

  float* S = ws + OFF_S + (size_t)blk * SSZ;
  if (w == 0) S[e] = acc0;  // d = 0
#pragma unroll
  for (int m = 0; m < 4; m++) {
    int il = w + 4 * m;
    S[(size_t)(1 + il) * HDIM + e] = accL[m] * INV_RRD;
#pragma unroll
    for (int j = 0; j < 16; j++)
      S[(size_t)(17 + il * 16 + j) * HDIM + e] = acc2[m][j] * INV_Q;
  }

  float* zk = ws + OFF_ZK + (size_t)blk * DFEAT;
  for (int d = tid; d < DFEAT; d += 256) {
    float sum;
    if (d == 0) {
      sum = (float)CHK;
    } else if (d < 17) {
      int i = d - 1;
      sum = 0.f;
      for (int c = 0; c < CHK; c++) sum += kc[c][i];
      sum *= INV_RRD;
    } else {
      int d2 = d - 17, i = d2 >> 4, j = d2 & 15;
      sum = 0.f;
      for (int c = 0; c < CHK; c++) sum += kc[c][i] * kc[c][j];
      sum *= INV_Q;
    }
    zk[d] = sum;
  }
}

// ---------------------------------------------------------------------------
// Exclusive prefix scan over the chunk axis for S and zk (per (b,h)).
// ---------------------------------------------------------------------------
__global__ __launch_bounds__(256) void scan_kernel(float* __restrict__ ws) {
  const int bh = blockIdx.y;
  const int E = blockIdx.x * 256 + threadIdx.x;
  if (E < SSZ) {
    float* base = ws + OFF_S + (size_t)bh * NCH * SSZ + E;
    float run = 0.f;
    for (int nc = 0; nc < NCH; nc++) {
      float v = base[(size_t)nc * SSZ];
      base[(size_t)nc * SSZ] = run;
      run += v;
    }
  } else if (E < SSZ + DFEAT) {
    int E2 = E - SSZ;
    float* base = ws + OFF_ZK + (size_t)bh * NCH * DFEAT + E2;
    float run = 0.f;
    for (int nc = 0; nc < NCH; nc++) {
      float v = base[nc * DFEAT];
      base[nc * DFEAT] = run;
      run += v;
    }
  }
}

// ---------------------------------------------------------------------------
// Per-chunk output: y = (qf @ S_prefix + tril(f(QK^T)) @ V) / denom.
// ---------------------------------------------------------------------------
__global__ __launch_bounds__(256) void chunk_out_kernel(float* __restrict__ ws) {
  __shared__ float qc[CHK][17];
  __shared__ float kc[CHK][17];
  __shared__ float vc[CHK][HDIM];
  __shared__ float qfT[64][64];
  __shared__ float SpT[64][64];
  __shared__ float zpT[64];
  __shared__ float zbuf[CHK];

  const int tid = threadIdx.x;
  const int blk = blockIdx.x;
  const int bh = blk / NCH, nc = blk % NCH;
  const int bb = bh >> 4, h = bh & 15;

  const float* qg = ws + OFF_Q + ((size_t)bh * LL + nc * CHK) * FDIM;
  const float* kg = ws + OFF_K + ((size_t)bh * LL + nc * CHK) * FDIM;
  const float* vg = ws + OFF_V + ((size_t)bh * LL + nc * CHK) * HDIM;
  const float* Sp = ws + OFF_S + (size_t)blk * SSZ;
  const float* zp = ws + OFF_ZK + (size_t)blk * DFEAT;

  {
    int c = tid >> 2, u = (tid & 3) * 4;
    float4 t4 = *(const float4*)&qg[c * FDIM + u];
    qc[c][u] = t4.x; qc[c][u + 1] = t4.y; qc[c][u + 2] = t4.z; qc[c][u + 3] = t4.w;
    float4 s4 = *(const float4*)&kg[c * FDIM + u];
    kc[c][u] = s4.x; kc[c][u + 1] = s4.y; kc[c][u + 2] = s4.z; kc[c][u + 3] = s4.w;
  }
#pragma unroll
  for (int s = 0; s < 4; s++) {
    int idx = tid * 4 + s * 1024;
    *(float4*)&((float*)vc)[idx] = *(const float4*)&vg[idx];
  }
  __syncthreads();

  const int tc = tid & 15, te = tid >> 4;
  float acc[4][4];
#pragma unroll
  for (int i = 0; i < 4; i++)
#pragma unroll
    for (int j = 0; j < 4; j++) acc[i][j] = 0.f;
  float zacc = 0.f;

  for (int t5 = 0; t5 < 5; t5++) {
    const int d0 = t5 * 64;
#pragma unroll
    for (int u = 0; u < 16; u++) {
      int idx = tid + u * 256;
      int dd = idx >> 6, c = idx & 63;
      int d = d0 + dd;
      float val;
      if (d >= DFEAT) val = 0.f;
      else if (d == 0) val = 1.f;
      else if (d < 17) val = qc[c][d - 1] * INV_RRD;
      else { int d2 = d - 17; val = qc[c][d2 >> 4] * qc[c][d2 & 15] * INV_Q; }
      qfT[dd][c] = val;
    }
#pragma unroll
    for (int u = 0; u < 4; u++) {
      int idx = tid + u * 256;
      int dd = idx >> 4, ev = (idx & 15) * 4;
      int d = d0 + dd;
      float4 sv;
      if (d < DFEAT) sv = *(const float4*)&Sp[(size_t)d * HDIM + ev];
      else sv = make_float4(0.f, 0.f, 0.f, 0.f);
      *(float4*)&SpT[dd][ev] = sv;
    }
    if (tid < 64) {
      int d = d0 + tid;
      zpT[tid] = (d < DFEAT) ? zp[d] : 0.f;
    }
    __syncthreads();
#pragma unroll 8
    for (int dd = 0; dd < 64; dd++) {
      float4 a4 = *(const float4*)&qfT[dd][tc * 4];
      float4 b4 = *(const float4*)&SpT[dd][te * 4];
      float aa[4] = {a4.x, a4.y, a4.z, a4.w};
      float bv[4] = {b4.x, b4.y, b4.z, b4.w};
#pragma unroll
      for (int i = 0; i < 4; i++)
#pragma unroll
        for (int j = 0; j < 4; j++) acc[i][j] = fmaf(aa[i], bv[j], acc[i][j]);
    }
    if (tid < 64) {
#pragma unroll 8
      for (int dd = 0; dd < 64; dd++) zacc = fmaf(qfT[dd][tid], zpT[dd], zacc);
    }
    __syncthreads();
  }

  {
    float sdot[4][4];
#pragma unroll
    for (int i = 0; i < 4; i++)
#pragma unroll
      for (int p = 0; p < 4; p++) sdot[i][p] = 0.f;
#pragma unroll
    for (int kk = 0; kk < 16; kk++) {
      float qv[4], kv[4];
#pragma unroll
      for (int i = 0; i < 4; i++) qv[i] = qc[tc * 4 + i][kk];
#pragma unroll
      for (int p = 0; p < 4; p++) kv[p] = kc[te * 4 + p][kk];
#pragma unroll
      for (int i = 0; i < 4; i++)
#pragma unroll
        for (int p = 0; p < 4; p++) sdot[i][p] = fmaf(qv[i], kv[p], sdot[i][p]);
    }
#pragma unroll
    for (int i = 0; i < 4; i++)
#pragma unroll
      for (int p = 0; p < 4; p++) {
        int ci = tc * 4 + i, cp = te * 4 + p;
        float s = sdot[i][p] * 0.25f;
        float f = 1.f + s + 0.5f * s * s;
        SpT[cp][ci] = (cp <= ci) ? f : 0.f;
      }
  }
  __syncthreads();

#pragma unroll 8
  for (int cc = 0; cc < 64; cc++) {
    float4 a4 = *(const float4*)&SpT[cc][tc * 4];
    float4 b4 = *(const float4*)&vc[cc][te * 4];
    float aa[4] = {a4.x, a4.y, a4.z, a4.w};
    float bv[4] = {b4.x, b4.y, b4.z, b4.w};
#pragma unroll
    for (int i = 0; i < 4; i++)
#pragma unroll
      for (int j = 0; j < 4; j++) acc[i][j] = fmaf(aa[i], bv[j], acc[i][j]);
  }
  if (tid < 64) {
    float zs = zacc;
#pragma unroll 8
    for (int cc = 0; cc < 64; cc++) zs += SpT[cc][tid];
    zbuf[tid] = zs;
  }
  __syncthreads();

  float* y = ws + OFF_Y;
#pragma unroll
  for (int i = 0; i < 4; i++) {
    int c = tc * 4 + i;
    float sc = 1.f / (zbuf[c] + EPSV);
    int p = nc * CHK + c;
    float4 o = make_float4(acc[i][0] * sc, acc[i][1] * sc, acc[i][2] * sc,
                           acc[i][3] * sc);
    *(float4*)&y[((size_t)bb * LL + p) * DMODEL + h * HDIM + te * 4] = o;
  }
}

// ---------------------------------------------------------------------------
extern "C" void kernel_launch(void* const* d_in, const int* in_sizes, int n_in,
                              void* d_out, int out_size, void* d_ws,
                              size_t ws_size, hipStream_t stream) {
  (void)in_sizes; (void)n_in; (void)out_size; (void)ws_size;
  const float* x  = (const float*)d_in[0];
  const float* Wq = (const float*)d_in[1];
  const float* Wk = (const float*)d_in[2];
  const float* Wv = (const float*)d_in[3];
  const float* Wo = (const float*)d_in[4];
  float* ws = (float*)d_ws;
  float* out = (float*)d_out;

  short* BThi = (short*)(ws + OFF_S);              // 1536*1024 bf16
  short* BTlo = BThi + (size_t)1536 * 1024;
  short* WoThi = (short*)(ws + OFF_Q);             // 1024*1024 bf16
  short* WoTlo = (short*)(ws + OFF_K);

  // 1) transpose+split Wq|Wk|Wv into BT (lives in dead S region)
  tsplit_qkv_kernel<<<dim3(32, 48), 256, 0, stream>>>(Wq, Wk, Wv, BThi, BTlo);
  // 2) fused q/k/v projection via split-bf16 MFMA, scatter to (b,h,l,d)
  mfma_gemm_kernel<0><<<dim3(12, 32), 256, 0, stream>>>(x, BThi, BTlo, ws);
  // 3) per-chunk states (overwrites BT region)
  chunk_state_kernel<<<dim3(BHN * NCH), 256, 0, stream>>>(ws);
  // 4) exclusive prefix scan over chunks
  scan_kernel<<<dim3(70, BHN), 256, 0, stream>>>(ws);
  // 5) inter + intra + normalize -> y
  chunk_out_kernel<<<dim3(BHN * NCH), 256, 0, stream>>>(ws);
  // 6) transpose+split Wo into dead Q/K regions
  tsplit_wo_kernel<<<dim3(32, 32), 256, 0, stream>>>(Wo, WoThi, WoTlo);
  // 7) out = y @ Wo via split-bf16 MFMA
  mfma_gemm_kernel<1><<<dim3(8, 32), 256, 0, stream>>>(ws + OFF_Y, WoThi,
                                                       WoTlo, out);
}

// Round 3
// 260.156 us; speedup vs baseline: 1.8965x; 1.3154x over previous
//
#include <hip/hip_runtime.h>

#define BB 2
#define LL 2048
#define DMODEL 1024
#define NH 16
#define FDIM 16
#define HDIM 64
#define DFEAT 273            // 1 + 16 + 256
#define CHK 64
#define NCH 32
#define BHN 32
#define SSZ (DFEAT * HDIM)   // 17472 (used for [e][273] transposed blocks too)
#define EPSV 1e-12f
#define INV_RRD 0.5f
#define INV_Q 0.17677669529663687f

// workspace layout (float offsets) — total 28,656,640 floats (114.6 MB), same as r1/r2
#define OFF_Q  ((size_t)0)                       // q fp32 [bh][l][16]; later WoThi
#define OFF_K  ((size_t)1048576)                 // k fp32;            later WoTlo
#define OFF_VT ((size_t)2097152)                 // vTh/vTl bf16 [bh][e][L] (2 x 4,194,304 shorts)
#define OFF_S  ((size_t)6291456)                 // S^T [bh][nc][e][273] fp32 -> packed u32 by scan
                                                 //   head also hosts BThi/BTlo + xh/xl during gemm<0>
#define OFF_ZK ((size_t)24182784)                // zk fp32 [bh][nc][273]
#define OFF_Y  ((size_t)24462336)                // yh/yl bf16 (2 x 4,194,304 shorts)

typedef __attribute__((ext_vector_type(8))) short s16x8;
typedef __attribute__((ext_vector_type(4))) float f32x4;

#define MFMA16(a, b, c) __builtin_amdgcn_mfma_f32_16x16x32_bf16(a, b, c, 0, 0, 0)

__device__ __forceinline__ void bsplit(float a, short& h, short& l) {
  unsigned int u = __float_as_uint(a);
  unsigned int hu = (u + 0x8000u) >> 16;
  float hf = __uint_as_float(hu << 16);
  float r = a - hf;
  unsigned int ru = __float_as_uint(r);
  h = (short)hu;
  l = (short)((ru + 0x8000u) >> 16);
}

__device__ __forceinline__ void llds16(const short* g, short* s) {
  __builtin_amdgcn_global_load_lds(
      (const __attribute__((address_space(1))) short*)g,
      (__attribute__((address_space(3))) short*)s, 16, 0, 0);
}

// feature map value: phi(row c of m)[d]
__device__ __forceinline__ float featv(const float (*m)[17], int c, int d) {
  if (d == 0) return 1.f;
  if (d < 17) return m[c][d - 1] * INV_RRD;
  if (d < DFEAT) { int d2 = d - 17; return m[c][d2 >> 4] * m[c][d2 & 15] * INV_Q; }
  return 0.f;
}

// ---------------------------------------------------------------------------
// x -> xh/xl bf16 split (elementwise)
// ---------------------------------------------------------------------------
__global__ __launch_bounds__(256) void xsplit_kernel(const float* __restrict__ x,
                                                     short* __restrict__ xh,
                                                     short* __restrict__ xl) {
  int i = (blockIdx.x * 256 + threadIdx.x) * 4;
  float4 v = *(const float4*)&x[i];
  short4 h, l;
  bsplit(v.x, h.x, l.x);
  bsplit(v.y, h.y, l.y);
  bsplit(v.z, h.z, l.z);
  bsplit(v.w, h.w, l.w);
  *(short4*)&xh[i] = h;
  *(short4*)&xl[i] = l;
}

// ---------------------------------------------------------------------------
// Transpose + split [Wq|Wk|Wv] into BT[n][k] hi/lo  (n<256 q, <512 k, else v)
// ---------------------------------------------------------------------------
__global__ __launch_bounds__(256) void tsplit_qkv_kernel(
    const float* __restrict__ Wq, const float* __restrict__ Wk,
    const float* __restrict__ Wv, short* __restrict__ dhi,
    short* __restrict__ dlo) {
  __shared__ float tile[32][33];
  const int k0 = blockIdx.x * 32, n0 = blockIdx.y * 32;
  const float* src; int nc, c0;
  if (n0 < 256)      { src = Wq; nc = 256;  c0 = n0; }
  else if (n0 < 512) { src = Wk; nc = 256;  c0 = n0 - 256; }
  else               { src = Wv; nc = 1024; c0 = n0 - 512; }
  const int t = threadIdx.x;
  {
    int kk = t >> 3, c4 = (t & 7) * 4;
    float4 v = *(const float4*)&src[(size_t)(k0 + kk) * nc + c0 + c4];
    tile[kk][c4] = v.x; tile[kk][c4 + 1] = v.y;
    tile[kk][c4 + 2] = v.z; tile[kk][c4 + 3] = v.w;
  }
  __syncthreads();
  int cc = t >> 3, k4 = (t & 7) * 4;
  short4 h4, l4;
  bsplit(tile[k4 + 0][cc], h4.x, l4.x);
  bsplit(tile[k4 + 1][cc], h4.y, l4.y);
  bsplit(tile[k4 + 2][cc], h4.z, l4.z);
  bsplit(tile[k4 + 3][cc], h4.w, l4.w);
  size_t o = (size_t)(n0 + cc) * 1024 + k0 + k4;
  *(short4*)&dhi[o] = h4;
  *(short4*)&dlo[o] = l4;
}

__global__ __launch_bounds__(256) void tsplit_wo_kernel(
    const float* __restrict__ Wo, short* __restrict__ dhi,
    short* __restrict__ dlo) {
  __shared__ float tile[32][33];
  const int k0 = blockIdx.x * 32, n0 = blockIdx.y * 32;
  const int t = threadIdx.x;
  {
    int kk = t >> 3, c4 = (t & 7) * 4;
    float4 v = *(const float4*)&Wo[(size_t)(k0 + kk) * 1024 + n0 + c4];
    tile[kk][c4] = v.x; tile[kk][c4 + 1] = v.y;
    tile[kk][c4 + 2] = v.z; tile[kk][c4 + 3] = v.w;
  }
  __syncthreads();
  int cc = t >> 3, k4 = (t & 7) * 4;
  short4 h4, l4;
  bsplit(tile[k4 + 0][cc], h4.x, l4.x);
  bsplit(tile[k4 + 1][cc], h4.y, l4.y);
  bsplit(tile[k4 + 2][cc], h4.z, l4.z);
  bsplit(tile[k4 + 3][cc], h4.w, l4.w);
  size_t o = (size_t)(n0 + cc) * 1024 + k0 + k4;
  *(short4*)&dhi[o] = h4;
  *(short4*)&dlo[o] = l4;
}

// ---------------------------------------------------------------------------
// Pure-bf16 split-precision GEMM, 128x64 tile, BK=64, global_load_lds staging
// with XOR-swizzled source (linear LDS dest). 3 MFMAs/frag (hh, hl, lh).
// MODE 0: scatter q/k fp32 + vT bf16-split. MODE 1: plain fp32 store.
// ---------------------------------------------------------------------------
template <int MODE>
__global__ __launch_bounds__(256) void bgemm_kernel(
    const short* __restrict__ Ah, const short* __restrict__ Al,
    const short* __restrict__ Bh, const short* __restrict__ Bl,
    float* __restrict__ dst, short* __restrict__ vTh, short* __restrict__ vTl) {
  // LDS (shorts): Ah[0,8192) Al[8192,16384) Bh[16384,20480) Bl[20480,24576)
  __shared__ short lds[24576];
  const int t = threadIdx.x;
  const int w = t >> 6, l = t & 63;
  const int m0 = blockIdx.y * 128, n0 = blockIdx.x * 64;
  const int g8 = ((l & 7) ^ (l >> 3)) * 8;  // swizzled global k-slot
  const int rsub = l >> 3;
  const int fr = l & 15, ks = l >> 4;
  const int wr = w >> 1, wc = w & 1;
  const int sw = fr & 7;

  f32x4 acc[4][2];
#pragma unroll
  for (int i = 0; i < 4; i++)
#pragma unroll
    for (int j = 0; j < 2; j++) acc[i][j] = (f32x4){0.f, 0.f, 0.f, 0.f};

  for (int k0 = 0; k0 < 1024; k0 += 64) {
    // stage 48KB: A 16 chunks of 1KB, B 8 chunks; wave w: A c=w*4+j, B c=w*2+j
#pragma unroll
    for (int j = 0; j < 4; j++) {
      const int c = w * 4 + j;
      const size_t ga = (size_t)(m0 + c * 8 + rsub) * 1024 + k0 + g8;
      llds16(Ah + ga, &lds[c * 512]);
      llds16(Al + ga, &lds[8192 + c * 512]);
    }
#pragma unroll
    for (int j = 0; j < 2; j++) {
      const int c = w * 2 + j;
      const size_t gb = (size_t)(n0 + c * 8 + rsub) * 1024 + k0 + g8;
      llds16(Bh + gb, &lds[16384 + c * 512]);
      llds16(Bl + gb, &lds[20480 + c * 512]);
    }
    __syncthreads();
#pragma unroll
    for (int kk = 0; kk < 2; kk++) {
      const int so = ((kk * 4 + ks) ^ sw) * 8;
      s16x8 fah[4], fal[4], fbh[2], fbl[2];
#pragma unroll
      for (int mi = 0; mi < 4; mi++) {
        const int ro = (wr * 64 + mi * 16 + fr) * 64 + so;
        fah[mi] = *(const s16x8*)&lds[ro];
        fal[mi] = *(const s16x8*)&lds[8192 + ro];
      }
#pragma unroll
      for (int ni = 0; ni < 2; ni++) {
        const int ro = (wc * 32 + ni * 16 + fr) * 64 + so;
        fbh[ni] = *(const s16x8*)&lds[16384 + ro];
        fbl[ni] = *(const s16x8*)&lds[20480 + ro];
      }
#pragma unroll
      for (int mi = 0; mi < 4; mi++)
#pragma unroll
        for (int ni = 0; ni < 2; ni++) {
          acc[mi][ni] = MFMA16(fah[mi], fbh[ni], acc[mi][ni]);
          acc[mi][ni] = MFMA16(fah[mi], fbl[ni], acc[mi][ni]);
          acc[mi][ni] = MFMA16(fal[mi], fbh[ni], acc[mi][ni]);
        }
    }
    __syncthreads();
  }

  // epilogue: C frag col = fr, row = ks*4 + r
  const int bb = m0 >> 11;
  const int lb = (m0 & (LL - 1)) + wr * 64;
#pragma unroll
  for (int mi = 0; mi < 4; mi++) {
    const int lrow = lb + mi * 16 + ks * 4;
    const int grow = m0 + wr * 64 + mi * 16 + ks * 4;
#pragma unroll
    for (int ni = 0; ni < 2; ni++) {
      const int cn = n0 + wc * 32 + ni * 16 + fr;
      if (MODE == 1) {
#pragma unroll
        for (int r = 0; r < 4; r++)
          dst[(size_t)(grow + r) * 1024 + cn] = acc[mi][ni][r];
      } else if (cn < 256) {
        const int hq = cn >> 4, f = cn & 15;
#pragma unroll
        for (int r = 0; r < 4; r++)
          dst[OFF_Q + ((size_t)(bb * NH + hq) * LL + lrow + r) * FDIM + f] =
              acc[mi][ni][r];
      } else if (cn < 512) {
        const int c2 = cn - 256, hq = c2 >> 4, f = c2 & 15;
#pragma unroll
        for (int r = 0; r < 4; r++)
          dst[OFF_K + ((size_t)(bb * NH + hq) * LL + lrow + r) * FDIM + f] =
              acc[mi][ni][r];
      } else {
        const int c2 = cn - 512, hh = c2 >> 6, e = c2 & 63;
        short4 hv, lv;
        bsplit(acc[mi][ni][0], hv.x, lv.x);
        bsplit(acc[mi][ni][1], hv.y, lv.y);
        bsplit(acc[mi][ni][2], hv.z, lv.z);
        bsplit(acc[mi][ni][3], hv.w, lv.w);
        const size_t o = ((size_t)(bb * NH + hh) * 64 + e) * LL + lrow;
        *(short4*)&vTh[o] = hv;
        *(short4*)&vTl[o] = lv;
      }
    }
  }
}

// ---------------------------------------------------------------------------
// Per-chunk states via MFMA: S^T[e][d] = sum_c kf[c][d] v[c][e]; zk[d] sums.
// ---------------------------------------------------------------------------
__global__ __launch_bounds__(256) void chunk_state_kernel(
    float* __restrict__ ws, const short* __restrict__ vTh,
    const short* __restrict__ vTl) {
  __shared__ float kc[64][17];
  __shared__ short kfh[64][72], kfl[64][72];
  __shared__ short vth[64][72], vtl[64][72];
  __shared__ float zred[64][4];
  const int t = threadIdx.x;
  const int blk = blockIdx.x;
  const int bh = blk >> 5, nc = blk & 31;

  {  // load k fp32
    int c = t >> 2, u = (t & 3) * 4;
    float4 v = *(const float4*)&ws[OFF_K + ((size_t)bh * LL + nc * 64 + c) * 16 + u];
    kc[c][u] = v.x; kc[c][u + 1] = v.y; kc[c][u + 2] = v.z; kc[c][u + 3] = v.w;
  }
  {  // stage vT bf16 (rows e, contiguous c)
    int e = t >> 2, cs = (t & 3) * 16;
    const short* sh = vTh + ((size_t)bh * 64 + e) * LL + nc * 64 + cs;
    const short* sl = vTl + ((size_t)bh * 64 + e) * LL + nc * 64 + cs;
    *(s16x8*)&vth[e][cs] = *(const s16x8*)sh;
    *(s16x8*)&vth[e][cs + 8] = *(const s16x8*)(sh + 8);
    *(s16x8*)&vtl[e][cs] = *(const s16x8*)sl;
    *(s16x8*)&vtl[e][cs + 8] = *(const s16x8*)(sl + 8);
  }
  __syncthreads();

  const int w = t >> 6, l = t & 63, fr = l & 15, ks = l >> 4;
  float* ST = ws + OFF_S + (size_t)blk * SSZ;   // [e][273]
  float* zk = ws + OFF_ZK + (size_t)blk * DFEAT;

  for (int t5 = 0; t5 < 5; t5++) {
    const int d0 = t5 * 64;
    {  // build kfT[dd][c] hi/lo, plus z partial sums
      const int dd = t >> 2, cq = t & 3;
      const int d = d0 + dd;
      float zs = 0.f;
#pragma unroll
      for (int j8 = 0; j8 < 8; j8++) {
        int c = cq * 2 + j8 * 8;
        float v0 = featv(kc, c, d), v1 = featv(kc, c + 1, d);
        zs += v0 + v1;
        short h0, l0, h1, l1;
        bsplit(v0, h0, l0);
        bsplit(v1, h1, l1);
        *(unsigned int*)&kfh[dd][c] =
            ((unsigned int)(unsigned short)h1 << 16) | (unsigned short)h0;
        *(unsigned int*)&kfl[dd][c] =
            ((unsigned int)(unsigned short)l1 << 16) | (unsigned short)l0;
      }
      zred[dd][cq] = zs;
    }
    __syncthreads();
    // MFMA: wave w -> d-rows d0 + w*16 .., 4 col-frags, K=64
    f32x4 sacc[4];
#pragma unroll
    for (int i = 0; i < 4; i++) sacc[i] = (f32x4){0.f, 0.f, 0.f, 0.f};
    const int arow = w * 16 + fr;
    s16x8 kah[2], kal[2];
#pragma unroll
    for (int kk = 0; kk < 2; kk++) {
      kah[kk] = *(const s16x8*)&kfh[arow][kk * 32 + ks * 8];
      kal[kk] = *(const s16x8*)&kfl[arow][kk * 32 + ks * 8];
    }
#pragma unroll
    for (int ni = 0; ni < 4; ni++)
#pragma unroll
      for (int kk = 0; kk < 2; kk++) {
        s16x8 vbh = *(const s16x8*)&vth[ni * 16 + fr][kk * 32 + ks * 8];
        s16x8 vbl = *(const s16x8*)&vtl[ni * 16 + fr][kk * 32 + ks * 8];
        sacc[ni] = MFMA16(kah[kk], vbh, sacc[ni]);
        sacc[ni] = MFMA16(kah[kk], vbl, sacc[ni]);
        sacc[ni] = MFMA16(kal[kk], vbh, sacc[ni]);
      }
    // store S^T[e][d] (guard only last tile)
    const int dbase = d0 + w * 16 + ks * 4;
#pragma unroll
    for (int ni = 0; ni < 4; ni++) {
      const int e = ni * 16 + fr;
      float* dp = ST + (size_t)e * DFEAT + dbase;
      if (t5 < 4) {
#pragma unroll
        for (int r = 0; r < 4; r++) dp[r] = sacc[ni][r];
      } else {
#pragma unroll
        for (int r = 0; r < 4; r++)
          if (dbase + r < DFEAT) dp[r] = sacc[ni][r];
      }
    }
    if (t < 64) {
      int d = d0 + t;
      if (d < DFEAT)
        zk[d] = zred[t][0] + zred[t][1] + zred[t][2] + zred[t][3];
    }
    __syncthreads();
  }
}

// ---------------------------------------------------------------------------
// Exclusive prefix over chunks; S^T packed in place as bf16 hi|lo u32.
// ---------------------------------------------------------------------------
__global__ __launch_bounds__(256) void scan_kernel(float* __restrict__ ws) {
  const int bh = blockIdx.y;
  const int E = blockIdx.x * 256 + threadIdx.x;
  if (E < SSZ) {
    float* base = ws + OFF_S + (size_t)bh * NCH * SSZ + E;
    unsigned int* basep = (unsigned int*)base;
    float run = 0.f;
    for (int nc = 0; nc < NCH; nc++) {
      float v = base[(size_t)nc * SSZ];
      short h, lo;
      bsplit(run, h, lo);
      basep[(size_t)nc * SSZ] =
          ((unsigned int)(unsigned short)h << 16) | (unsigned short)lo;
      run += v;
    }
  } else if (E < SSZ + DFEAT) {
    int E2 = E - SSZ;
    float* base = ws + OFF_ZK + (size_t)bh * NCH * DFEAT + E2;
    float run = 0.f;
    for (int nc = 0; nc < NCH; nc++) {
      float v = base[nc * DFEAT];
      base[nc * DFEAT] = run;
      run += v;
    }
  }
}

// ---------------------------------------------------------------------------
// Per-chunk output via MFMA: y = (qf@Sp + tril(f(QK^T))@V) / z -> yh/yl bf16.
// ---------------------------------------------------------------------------
__global__ __launch_bounds__(256) void chunk_out_kernel(
    float* __restrict__ ws, const short* __restrict__ vTh,
    const short* __restrict__ vTl, short* __restrict__ yh,
    short* __restrict__ yl) {
  __shared__ float qc[64][17], kc[64][17];
  __shared__ short qfh[64][72], qfl[64][72];  // qf tiles; later f (intra)
  __shared__ short sph[64][72], spl[64][72];  // Sp^T tile [e][d]
  __shared__ short vth[64][72], vtl[64][72];
  __shared__ float zpf[64];                   // zp tile; later 1/z
  __shared__ float zred[64][4];
  const int t = threadIdx.x;
  const int blk = blockIdx.x;
  const int bh = blk >> 5, nc = blk & 31;
  const int bb = bh >> 4, h = bh & 15;

  {  // load q,k fp32
    int c = t >> 2, u = (t & 3) * 4;
    float4 v = *(const float4*)&ws[OFF_Q + ((size_t)bh * LL + nc * 64 + c) * 16 + u];
    qc[c][u] = v.x; qc[c][u + 1] = v.y; qc[c][u + 2] = v.z; qc[c][u + 3] = v.w;
    float4 s = *(const float4*)&ws[OFF_K + ((size_t)bh * LL + nc * 64 + c) * 16 + u];
    kc[c][u] = s.x; kc[c][u + 1] = s.y; kc[c][u + 2] = s.z; kc[c][u + 3] = s.w;
  }
  {  // stage vT
    int e = t >> 2, cs = (t & 3) * 16;
    const short* sh = vTh + ((size_t)bh * 64 + e) * LL + nc * 64 + cs;
    const short* sl = vTl + ((size_t)bh * 64 + e) * LL + nc * 64 + cs;
    *(s16x8*)&vth[e][cs] = *(const s16x8*)sh;
    *(s16x8*)&vth[e][cs + 8] = *(const s16x8*)(sh + 8);
    *(s16x8*)&vtl[e][cs] = *(const s16x8*)sl;
    *(s16x8*)&vtl[e][cs + 8] = *(const s16x8*)(sl + 8);
  }
  __syncthreads();

  const unsigned int* SpP = (const unsigned int*)(ws + OFF_S + (size_t)blk * SSZ);
  const float* zp = ws + OFF_ZK + (size_t)blk * DFEAT;
  const int w = t >> 6, l = t & 63, fr = l & 15, ks = l >> 4;
  const int cz = t & 63, qz = t >> 6;

  f32x4 acc[4];
#pragma unroll
  for (int i = 0; i < 4; i++) acc[i] = (f32x4){0.f, 0.f, 0.f, 0.f};
  float zpart = 0.f;

  for (int t5 = 0; t5 < 5; t5++) {
    const int d0 = t5 * 64;
    {  // build qf[c][dd] hi/lo
      const int c = t >> 2, dq = t & 3;
#pragma unroll
      for (int j8 = 0; j8 < 8; j8++) {
        int dd = dq * 2 + j8 * 8;
        int d = d0 + dd;
        float v0 = featv(qc, c, d), v1 = featv(qc, c, d + 1);
        short h0, l0, h1, l1;
        bsplit(v0, h0, l0);
        bsplit(v1, h1, l1);
        *(unsigned int*)&qfh[c][dd] =
            ((unsigned int)(unsigned short)h1 << 16) | (unsigned short)h0;
        *(unsigned int*)&qfl[c][dd] =
            ((unsigned int)(unsigned short)l1 << 16) | (unsigned short)l0;
      }
    }
    {  // stage packed Sp^T tile -> sph/spl
      const int e = t >> 2, dq = t & 3;
      const unsigned int* sp = SpP + (size_t)e * DFEAT;
#pragma unroll
      for (int j8 = 0; j8 < 8; j8++) {
        int dd = dq * 2 + j8 * 8;
        int d = d0 + dd;
        unsigned int u0 = (d < DFEAT) ? sp[d] : 0u;
        unsigned int u1 = (d + 1 < DFEAT) ? sp[d + 1] : 0u;
        *(unsigned int*)&sph[e][dd] = (u0 >> 16) | (u1 & 0xffff0000u);
        *(unsigned int*)&spl[e][dd] = (u0 & 0xffffu) | (u1 << 16);
      }
    }
    if (t < 64) zpf[t] = (d0 + t < DFEAT) ? zp[d0 + t] : 0.f;
    __syncthreads();
    // inter MFMA: A=qf (rows c), B=Sp^T (cols e), K=64
    {
      const int arow = w * 16 + fr;
      s16x8 qh2[2], ql2[2];
#pragma unroll
      for (int kk = 0; kk < 2; kk++) {
        qh2[kk] = *(const s16x8*)&qfh[arow][kk * 32 + ks * 8];
        ql2[kk] = *(const s16x8*)&qfl[arow][kk * 32 + ks * 8];
      }
#pragma unroll
      for (int ni = 0; ni < 4; ni++)
#pragma unroll
        for (int kk = 0; kk < 2; kk++) {
          s16x8 sh = *(const s16x8*)&sph[ni * 16 + fr][kk * 32 + ks * 8];
          s16x8 sl = *(const s16x8*)&spl[ni * 16 + fr][kk * 32 + ks * 8];
          acc[ni] = MFMA16(qh2[kk], sh, acc[ni]);
          acc[ni] = MFMA16(qh2[kk], sl, acc[ni]);
          acc[ni] = MFMA16(ql2[kk], sh, acc[ni]);
        }
    }
    // z inter partial (exact fp32 recompute)
#pragma unroll
    for (int i = 0; i < 16; i++) {
      int dd = qz * 16 + i;
      zpart = fmaf(featv(qc, cz, d0 + dd), zpf[dd], zpart);
    }
    __syncthreads();
  }

  zred[cz][qz] = zpart;
  // intra: QK^T on VALU (K=16), f = 1+s+s^2/2, tril, write split-bf16 into qf LDS
  {
    const int tc = t & 15, te = t >> 4;
    float sdot[4][4];
#pragma unroll
    for (int i = 0; i < 4; i++)
#pragma unroll
      for (int p = 0; p < 4; p++) sdot[i][p] = 0.f;
#pragma unroll
    for (int kk = 0; kk < 16; kk++) {
      float qv[4], kv[4];
#pragma unroll
      for (int i = 0; i < 4; i++) qv[i] = qc[tc * 4 + i][kk];
#pragma unroll
      for (int p = 0; p < 4; p++) kv[p] = kc[te * 4 + p][kk];
#pragma unroll
      for (int i = 0; i < 4; i++)
#pragma unroll
        for (int p = 0; p < 4; p++) sdot[i][p] = fmaf(qv[i], kv[p], sdot[i][p]);
    }
#pragma unroll
    for (int i = 0; i < 4; i++)
#pragma unroll
      for (int p = 0; p < 4; p++) {
        int ci = tc * 4 + i, cp = te * 4 + p;
        float s = sdot[i][p] * 0.25f;
        float f = 1.f + s + 0.5f * s * s;
        f = (cp <= ci) ? f : 0.f;
        short fh, fl;
        bsplit(f, fh, fl);
        qfh[ci][cp] = fh;
        qfl[ci][cp] = fl;
      }
  }
  __syncthreads();
  // intra MFMA: A=f (rows ci), B=vT (cols e), K=64 — accumulates into acc
  {
    const int arow = w * 16 + fr;
    s16x8 fh2[2], fl2[2];
#pragma unroll
    for (int kk = 0; kk < 2; kk++) {
      fh2[kk] = *(const s16x8*)&qfh[arow][kk * 32 + ks * 8];
      fl2[kk] = *(const s16x8*)&qfl[arow][kk * 32 + ks * 8];
    }
#pragma unroll
    for (int ni = 0; ni < 4; ni++)
#pragma unroll
      for (int kk = 0; kk < 2; kk++) {
        s16x8 vbh = *(const s16x8*)&vth[ni * 16 + fr][kk * 32 + ks * 8];
        s16x8 vbl = *(const s16x8*)&vtl[ni * 16 + fr][kk * 32 + ks * 8];
        acc[ni] = MFMA16(fh2[kk], vbh, acc[ni]);
        acc[ni] = MFMA16(fh2[kk], vbl, acc[ni]);
        acc[ni] = MFMA16(fl2[kk], vbh, acc[ni]);
      }
  }
  // intra denominator partials: rowsums of f
  {
    const int ci = t >> 2, cq = t & 3;
    float zs = 0.f;
#pragma unroll
    for (int j8 = 0; j8 < 8; j8++) {
      int c = cq * 2 + j8 * 8;
      unsigned int uh = *(const unsigned int*)&qfh[ci][c];
      unsigned int ul = *(const unsigned int*)&qfl[ci][c];
      zs += __uint_as_float(uh << 16) + __uint_as_float(uh & 0xffff0000u);
      zs += __uint_as_float(ul << 16) + __uint_as_float(ul & 0xffff0000u);
    }
    zred[ci][cq] += zs;  // += over the inter partials (barrier separated)
  }
  __syncthreads();
  if (t < 64)
    zpf[t] = 1.f / (zred[t][0] + zred[t][1] + zred[t][2] + zred[t][3] + EPSV);
  __syncthreads();
  // epilogue: scale, split, store yh/yl
  {
    const int crow = w * 16 + ks * 4;
    float sc[4];
#pragma unroll
    for (int r = 0; r < 4; r++) sc[r] = zpf[crow + r];
#pragma unroll
    for (int ni = 0; ni < 4; ni++) {
      const int e = ni * 16 + fr;
      const size_t ybase =
          ((size_t)bb * LL + nc * 64 + crow) * DMODEL + h * 64 + e;
#pragma unroll
      for (int r = 0; r < 4; r++) {
        float v = acc[ni][r] * sc[r];
        short hh, ll;
        bsplit(v, hh, ll);
        yh[ybase + (size_t)r * DMODEL] = hh;
        yl[ybase + (size_t)r * DMODEL] = ll;
      }
    }
  }
}

// ---------------------------------------------------------------------------
extern "C" void kernel_launch(void* const* d_in, const int* in_sizes, int n_in,
                              void* d_out, int out_size, void* d_ws,
                              size_t ws_size, hipStream_t stream) {
  (void)in_sizes; (void)n_in; (void)out_size; (void)ws_size;
  const float* x  = (const float*)d_in[0];
  const float* Wq = (const float*)d_in[1];
  const float* Wk = (const float*)d_in[2];
  const float* Wv = (const float*)d_in[3];
  const float* Wo = (const float*)d_in[4];
  float* ws = (float*)d_ws;
  float* out = (float*)d_out;

  short* vTh = (short*)(ws + OFF_VT);
  short* vTl = vTh + (size_t)4194304;
  short* yh = (short*)(ws + OFF_Y);
  short* yl = yh + (size_t)4194304;
  // overlays in dead S region during projection phase
  short* BThi = (short*)(ws + OFF_S);
  short* BTlo = BThi + (size_t)1536 * 1024;
  short* xh = BTlo + (size_t)1536 * 1024;
  short* xl = xh + (size_t)4096 * 1024;
  // overlays in dead Q/K regions for the output projection
  short* WoThi = (short*)(ws + OFF_Q);
  short* WoTlo = (short*)(ws + OFF_K);

  xsplit_kernel<<<4096, 256, 0, stream>>>(x, xh, xl);
  tsplit_qkv_kernel<<<dim3(32, 48), 256, 0, stream>>>(Wq, Wk, Wv, BThi, BTlo);
  bgemm_kernel<0><<<dim3(24, 32), 256, 0, stream>>>(xh, xl, BThi, BTlo, ws,
                                                    vTh, vTl);
  chunk_state_kernel<<<dim3(BHN * NCH), 256, 0, stream>>>(ws, vTh, vTl);
  scan_kernel<<<dim3(70, BHN), 256, 0, stream>>>(ws);
  chunk_out_kernel<<<dim3(BHN * NCH), 256, 0, stream>>>(ws, vTh, vTl, yh, yl);
  tsplit_wo_kernel<<<dim3(32, 32), 256, 0, stream>>>(Wo, WoThi, WoTlo);
  bgemm_kernel<1><<<dim3(16, 32), 256, 0, stream>>>(yh, yl, WoThi, WoTlo, out,
                                                    nullptr, nullptr);
}

// Round 6
// 170.340 us; speedup vs baseline: 2.8965x; 1.5273x over previous
//
#include <hip/hip_runtime.h>

#define LL 2048
#define NH 16
#define DFEAT 273
#define SROW 320             // padded feature stride (f16 row of S / zk f32 row)
#define EPSV 1e-12f
#define INV_RRD 0.5f
#define INV_Q 0.17677669529663687f

// workspace layout (float offsets), total 17,104,896 floats = 68.4 MB
#define OFF_Q  ((size_t)0)          // q fp32 [bh][l][16]; later WoT f16 overlay
#define OFF_K  ((size_t)1048576)    // k fp32 [bh][l][16]
#define OFF_VT ((size_t)2097152)    // vT f16 [bh][e][L]  (4,194,304 f16)
#define OFF_S  ((size_t)4194304)    // S f16 [1024][64][SROW]; head hosts xf+BT overlays
#define OFF_ZK ((size_t)14680064)   // zk f32 [1024][SROW]
#define OFF_Y  ((size_t)15007744)   // y f16 [4096][1024]

typedef __attribute__((ext_vector_type(8))) _Float16 f16x8;
typedef __attribute__((ext_vector_type(4))) float f32x4;

#define MFMAH(a, b, c) __builtin_amdgcn_mfma_f32_16x16x32_f16(a, b, c, 0, 0, 0)

__device__ __forceinline__ void llds16(const _Float16* g, _Float16* s) {
  __builtin_amdgcn_global_load_lds(
      (const __attribute__((address_space(1))) short*)(const short*)g,
      (__attribute__((address_space(3))) short*)(short*)s, 16, 0, 0);
}

// phi(row c of m)[d], fp32
__device__ __forceinline__ float featv(const float (*m)[17], int c, int d) {
  if (d == 0) return 1.f;
  if (d < 17) return m[c][d - 1] * INV_RRD;
  if (d < DFEAT) { int d2 = d - 17; return m[c][d2 >> 4] * m[c][d2 & 15] * INV_Q; }
  return 0.f;
}

// ---------------------------------------------------------------------------
// x fp32 -> f16
// ---------------------------------------------------------------------------
__global__ __launch_bounds__(256) void xcvt_kernel(const float* __restrict__ x,
                                                   _Float16* __restrict__ xf) {
  int i = (blockIdx.x * 256 + threadIdx.x) * 8;
  float4 a = *(const float4*)&x[i];
  float4 b = *(const float4*)&x[i + 4];
  f16x8 o;
  o[0] = (_Float16)a.x; o[1] = (_Float16)a.y; o[2] = (_Float16)a.z;
  o[3] = (_Float16)a.w; o[4] = (_Float16)b.x; o[5] = (_Float16)b.y;
  o[6] = (_Float16)b.z; o[7] = (_Float16)b.w;
  *(f16x8*)&xf[i] = o;
}

// ---------------------------------------------------------------------------
// Transpose+cvt [Wq|Wk|Wv] -> BT[n][k] f16  (n<256 q, <512 k, else v)
// ---------------------------------------------------------------------------
__global__ __launch_bounds__(256) void tcvt_qkv_kernel(
    const float* __restrict__ Wq, const float* __restrict__ Wk,
    const float* __restrict__ Wv, _Float16* __restrict__ dst) {
  __shared__ float tile[32][33];
  const int k0 = blockIdx.x * 32, n0 = blockIdx.y * 32;
  const float* src; int ncol, c0;
  if (n0 < 256)      { src = Wq; ncol = 256;  c0 = n0; }
  else if (n0 < 512) { src = Wk; ncol = 256;  c0 = n0 - 256; }
  else               { src = Wv; ncol = 1024; c0 = n0 - 512; }
  const int t = threadIdx.x;
  {
    int kk = t >> 3, c4 = (t & 7) * 4;
    float4 v = *(const float4*)&src[(size_t)(k0 + kk) * ncol + c0 + c4];
    tile[kk][c4] = v.x; tile[kk][c4 + 1] = v.y;
    tile[kk][c4 + 2] = v.z; tile[kk][c4 + 3] = v.w;
  }
  __syncthreads();
  int cc = t >> 3, k4 = (t & 7) * 4;
  union { unsigned long long u; _Float16 f[4]; } p;
  p.f[0] = (_Float16)tile[k4 + 0][cc];
  p.f[1] = (_Float16)tile[k4 + 1][cc];
  p.f[2] = (_Float16)tile[k4 + 2][cc];
  p.f[3] = (_Float16)tile[k4 + 3][cc];
  *(unsigned long long*)&dst[(size_t)(n0 + cc) * 1024 + k0 + k4] = p.u;
}

__global__ __launch_bounds__(256) void tcvt_wo_kernel(
    const float* __restrict__ Wo, _Float16* __restrict__ dst) {
  __shared__ float tile[32][33];
  const int k0 = blockIdx.x * 32, n0 = blockIdx.y * 32;
  const int t = threadIdx.x;
  {
    int kk = t >> 3, c4 = (t & 7) * 4;
    float4 v = *(const float4*)&Wo[(size_t)(k0 + kk) * 1024 + n0 + c4];
    tile[kk][c4] = v.x; tile[kk][c4 + 1] = v.y;
    tile[kk][c4 + 2] = v.z; tile[kk][c4 + 3] = v.w;
  }
  __syncthreads();
  int cc = t >> 3, k4 = (t & 7) * 4;
  union { unsigned long long u; _Float16 f[4]; } p;
  p.f[0] = (_Float16)tile[k4 + 0][cc];
  p.f[1] = (_Float16)tile[k4 + 1][cc];
  p.f[2] = (_Float16)tile[k4 + 2][cc];
  p.f[3] = (_Float16)tile[k4 + 3][cc];
  *(unsigned long long*)&dst[(size_t)(n0 + cc) * 1024 + k0 + k4] = p.u;
}

// ---------------------------------------------------------------------------
// f16 MFMA GEMM, 128x64 tile, BK=64, global_load_lds staging (swizzled src).
// MODE 0: A=xf, B=BT(1536 rows) -> scatter q/k fp32 + vT f16.
// MODE 1: A=y,  B=WoT           -> fp32 out.
// ---------------------------------------------------------------------------
template <int MODE>
__global__ __launch_bounds__(256) void bgemm_kernel(
    const _Float16* __restrict__ A, const _Float16* __restrict__ B,
    float* __restrict__ dst, _Float16* __restrict__ vT) {
  __shared__ _Float16 lds[12288];  // A[0,8192) B[8192,12288)
  const int t = threadIdx.x;
  const int w = t >> 6, l = t & 63;
  const int m0 = blockIdx.y * 128, n0 = blockIdx.x * 64;
  const int rsub = l >> 3;
  const int g8 = ((l & 7) ^ rsub) * 8;
  const int fr = l & 15, ks = l >> 4;
  const int wr = w >> 1, wc = w & 1;

  f32x4 acc[4][2];
#pragma unroll
  for (int i = 0; i < 4; i++)
#pragma unroll
    for (int j = 0; j < 2; j++) acc[i][j] = (f32x4){0.f, 0.f, 0.f, 0.f};

  for (int k0 = 0; k0 < 1024; k0 += 64) {
#pragma unroll
    for (int j = 0; j < 4; j++) {
      const int c = w * 4 + j;
      llds16(A + (size_t)(m0 + c * 8 + rsub) * 1024 + k0 + g8, &lds[c * 512]);
    }
#pragma unroll
    for (int j = 0; j < 2; j++) {
      const int c = w * 2 + j;
      llds16(B + (size_t)(n0 + c * 8 + rsub) * 1024 + k0 + g8,
             &lds[8192 + c * 512]);
    }
    __syncthreads();
#pragma unroll
    for (int kk = 0; kk < 2; kk++) {
      const int so = ((kk * 4 + ks) ^ (fr & 7)) * 8;
      f16x8 fa[4], fb[2];
#pragma unroll
      for (int mi = 0; mi < 4; mi++)
        fa[mi] = *(const f16x8*)&lds[(wr * 64 + mi * 16 + fr) * 64 + so];
#pragma unroll
      for (int ni = 0; ni < 2; ni++)
        fb[ni] = *(const f16x8*)&lds[8192 + (wc * 32 + ni * 16 + fr) * 64 + so];
#pragma unroll
      for (int mi = 0; mi < 4; mi++)
#pragma unroll
        for (int ni = 0; ni < 2; ni++)
          acc[mi][ni] = MFMAH(fa[mi], fb[ni], acc[mi][ni]);
    }
    __syncthreads();
  }

  const int bb = m0 >> 11;
#pragma unroll
  for (int mi = 0; mi < 4; mi++) {
    const int lrow = (m0 & (LL - 1)) + wr * 64 + mi * 16 + ks * 4;
    const int grow = m0 + wr * 64 + mi * 16 + ks * 4;
#pragma unroll
    for (int ni = 0; ni < 2; ni++) {
      const int cn = n0 + wc * 32 + ni * 16 + fr;
      if (MODE == 1) {
#pragma unroll
        for (int r = 0; r < 4; r++)
          dst[(size_t)(grow + r) * 1024 + cn] = acc[mi][ni][r];
      } else if (cn < 256) {
        const int hq = cn >> 4, f = cn & 15;
#pragma unroll
        for (int r = 0; r < 4; r++)
          dst[OFF_Q + ((size_t)(bb * NH + hq) * LL + lrow + r) * 16 + f] =
              acc[mi][ni][r];
      } else if (cn < 512) {
        const int c2 = cn - 256, hq = c2 >> 4, f = c2 & 15;
#pragma unroll
        for (int r = 0; r < 4; r++)
          dst[OFF_K + ((size_t)(bb * NH + hq) * LL + lrow + r) * 16 + f] =
              acc[mi][ni][r];
      } else {
        const int c2 = cn - 512, hh = c2 >> 6, e = c2 & 63;
        union { unsigned long long u; _Float16 f[4]; } p;
#pragma unroll
        for (int r = 0; r < 4; r++) p.f[r] = (_Float16)acc[mi][ni][r];
        *(unsigned long long*)&vT[((size_t)(bb * NH + hh) * 64 + e) * LL +
                                  lrow] = p.u;
      }
    }
  }
}

// ---------------------------------------------------------------------------
// Per-chunk states: S[e][d] = sum_c kf[c][d] v[c][e] (f16 out), zk[d] sums.
// kf built per-lane directly in MFMA A-frag layout (no LDS build).
// ---------------------------------------------------------------------------
__global__ __launch_bounds__(256) void chunk_state_kernel(
    float* __restrict__ ws, const _Float16* __restrict__ vT) {
  __shared__ float kc[64][17];
  __shared__ _Float16 vt[4096];  // [64][64] swizzled
  const int t = threadIdx.x, blk = blockIdx.x;
  const int bh = blk >> 5, nc = blk & 31;
  const int w = t >> 6, l = t & 63;
  const int rsub = l >> 3, g8 = ((l & 7) ^ rsub) * 8;
  const int fr = l & 15, ks = l >> 4;

  {
    int c = t >> 2, u = (t & 3) * 4;
    float4 v =
        *(const float4*)&ws[OFF_K + ((size_t)bh * LL + nc * 64 + c) * 16 + u];
    kc[c][u] = v.x; kc[c][u + 1] = v.y; kc[c][u + 2] = v.z; kc[c][u + 3] = v.w;
  }
  const _Float16* vg = vT + (size_t)bh * 64 * LL + nc * 64;
#pragma unroll
  for (int j = 0; j < 2; j++) {
    const int c = w * 2 + j;
    llds16(vg + (size_t)(c * 8 + rsub) * LL + g8, &vt[c * 512]);
  }
  __syncthreads();

  _Float16* S16 = (_Float16*)(ws + OFF_S) + (size_t)blk * (64 * SROW);
  float* zk = ws + OFF_ZK + (size_t)blk * SROW;

  for (int t5 = 0; t5 < 5; t5++) {
    const int d0 = t5 * 64;
    const int d = d0 + w * 16 + fr;  // this lane's A-row (feature index)
    f16x8 af[2];
    float zpart = 0.f;
#pragma unroll
    for (int kk = 0; kk < 2; kk++)
#pragma unroll
      for (int j = 0; j < 8; j++) {
        float v = featv(kc, kk * 32 + ks * 8 + j, d);
        zpart += v;
        af[kk][j] = (_Float16)v;
      }
    zpart += __shfl_xor(zpart, 16);
    zpart += __shfl_xor(zpart, 32);
    if (ks == 0 && d < DFEAT) zk[d] = zpart;

    f32x4 sacc[4];
#pragma unroll
    for (int i = 0; i < 4; i++) sacc[i] = (f32x4){0.f, 0.f, 0.f, 0.f};
#pragma unroll
    for (int ni = 0; ni < 4; ni++)
#pragma unroll
      for (int kk = 0; kk < 2; kk++) {
        f16x8 fb = *(const f16x8*)&vt[(ni * 16 + fr) * 64 +
                                      (((kk * 4 + ks)) ^ (fr & 7)) * 8];
        sacc[ni] = MFMAH(af[kk], fb, sacc[ni]);
      }
    const int dstart = d0 + w * 16 + ks * 4;  // D-frag row base
#pragma unroll
    for (int ni = 0; ni < 4; ni++) {
      union { unsigned long long u; _Float16 f[4]; } p;
#pragma unroll
      for (int r = 0; r < 4; r++)
        p.f[r] = (dstart + r < DFEAT) ? (_Float16)sacc[ni][r] : (_Float16)0.f;
      *(unsigned long long*)&S16[(size_t)(ni * 16 + fr) * SROW + dstart] = p.u;
    }
  }
}

// ---------------------------------------------------------------------------
// Exclusive prefix over chunks: S (f16 pairs, f32 accum) and zk (f32).
// ---------------------------------------------------------------------------
__global__ __launch_bounds__(256) void scan_kernel(float* __restrict__ ws) {
  const int bh = blockIdx.y;
  const int E = blockIdx.x * 256 + threadIdx.x;
  const int SU = 64 * SROW / 2;  // 10240 u32 per chunk-block
  if (E < SU) {
    unsigned int* base =
        (unsigned int*)((_Float16*)(ws + OFF_S) + (size_t)bh * 32 * (64 * SROW)) +
        E;
    float r0 = 0.f, r1 = 0.f;
    for (int nc = 0; nc < 32; nc++) {
      union { unsigned int u; _Float16 f[2]; } in, ov;
      in.u = base[(size_t)nc * SU];
      float v0 = (float)in.f[0], v1 = (float)in.f[1];
      ov.f[0] = (_Float16)r0; ov.f[1] = (_Float16)r1;
      base[(size_t)nc * SU] = ov.u;
      r0 += v0; r1 += v1;
    }
  } else if (E < SU + SROW) {
    float* base = ws + OFF_ZK + (size_t)bh * 32 * SROW + (E - SU);
    float run = 0.f;
    for (int nc = 0; nc < 32; nc++) {
      float v = base[(size_t)nc * SROW];
      base[(size_t)nc * SROW] = run;
      run += v;
    }
  }
}

// ---------------------------------------------------------------------------
// Per-chunk output: y = (qf@Sp + tril(1+s+s^2/2)@V)/z -> y f16.
// qf/f fragments built in registers; QK^T via MFMA (K=32 zero-padded);
// f round-trips through the sp LDS buffer (swizzled).
// ---------------------------------------------------------------------------
__global__ __launch_bounds__(256) void chunk_out_kernel(
    float* __restrict__ ws, const _Float16* __restrict__ vT,
    _Float16* __restrict__ y) {
  __shared__ float qc[64][17], kc[64][17];
  __shared__ _Float16 vt[4096], sp[4096];
  __shared__ float zpf[64];
  __shared__ float zinv[64];
  const int t = threadIdx.x, blk = blockIdx.x;
  const int bh = blk >> 5, nc = blk & 31;
  const int bb = bh >> 4, h = bh & 15;
  const int w = t >> 6, l = t & 63;
  const int rsub = l >> 3, g8 = ((l & 7) ^ rsub) * 8;
  const int fr = l & 15, ks = l >> 4;
  const int crowA = w * 16 + fr;  // A-frag row this lane holds

  {
    int c = t >> 2, u = (t & 3) * 4;
    float4 v =
        *(const float4*)&ws[OFF_Q + ((size_t)bh * LL + nc * 64 + c) * 16 + u];
    qc[c][u] = v.x; qc[c][u + 1] = v.y; qc[c][u + 2] = v.z; qc[c][u + 3] = v.w;
    float4 s =
        *(const float4*)&ws[OFF_K + ((size_t)bh * LL + nc * 64 + c) * 16 + u];
    kc[c][u] = s.x; kc[c][u + 1] = s.y; kc[c][u + 2] = s.z; kc[c][u + 3] = s.w;
  }
  const _Float16* vg = vT + (size_t)bh * 64 * LL + nc * 64;
#pragma unroll
  for (int j = 0; j < 2; j++) {
    const int c = w * 2 + j;
    llds16(vg + (size_t)(c * 8 + rsub) * LL + g8, &vt[c * 512]);
  }

  const _Float16* Sp16 =
      (const _Float16*)(ws + OFF_S) + (size_t)blk * (64 * SROW);
  const float* zp = ws + OFF_ZK + (size_t)blk * SROW;

  f32x4 acc[4];
#pragma unroll
  for (int i = 0; i < 4; i++) acc[i] = (f32x4){0.f, 0.f, 0.f, 0.f};
  float zrow = 0.f;

  // ---- inter: y += qf @ Sp (5 d-tiles of 64)
  for (int t5 = 0; t5 < 5; t5++) {
    const int d0 = t5 * 64;
#pragma unroll
    for (int j = 0; j < 2; j++) {
      const int c = w * 2 + j;
      llds16(Sp16 + (size_t)(c * 8 + rsub) * SROW + d0 + g8, &sp[c * 512]);
    }
    if (t < 64) zpf[t] = (d0 + t < DFEAT) ? zp[d0 + t] : 0.f;
    __syncthreads();
    f16x8 af[2];
#pragma unroll
    for (int kk = 0; kk < 2; kk++)
#pragma unroll
      for (int j = 0; j < 8; j++) {
        const int dd = kk * 32 + ks * 8 + j;
        float v = featv(qc, crowA, d0 + dd);
        zrow = fmaf(v, zpf[dd], zrow);
        af[kk][j] = (_Float16)v;
      }
#pragma unroll
    for (int ni = 0; ni < 4; ni++)
#pragma unroll
      for (int kk = 0; kk < 2; kk++) {
        f16x8 fb = *(const f16x8*)&sp[(ni * 16 + fr) * 64 +
                                      (((kk * 4 + ks)) ^ (fr & 7)) * 8];
        acc[ni] = MFMAH(af[kk], fb, acc[ni]);
      }
    __syncthreads();
  }

  // ---- intra: s = (q.k)/4 via MFMA (K=32, upper half zero)
  {
    float qreg[16];
#pragma unroll
    for (int i = 0; i < 16; i++) qreg[i] = qc[crowA][i];
    f16x8 aq;
#pragma unroll
    for (int j = 0; j < 8; j++)
      aq[j] = (ks < 2) ? (_Float16)(0.25f * qreg[(ks * 8 + j) & 15])
                       : (_Float16)0.f;
    const f32x4 zero4 = {0.f, 0.f, 0.f, 0.f};
    f32x4 sD[4];
#pragma unroll
    for (int ni = 0; ni < 4; ni++) {
      f16x8 bk;
#pragma unroll
      for (int j = 0; j < 8; j++)
        bk[j] = (ks < 2) ? (_Float16)kc[ni * 16 + fr][(ks * 8 + j) & 15]
                         : (_Float16)0.f;
      sD[ni] = MFMAH(aq, bk, zero4);
    }
    // f = tril(1 + s + s^2/2) -> write into sp (swizzled) for A-frag reads
#pragma unroll
    for (int ni = 0; ni < 4; ni++) {
      const int cp = ni * 16 + fr;
#pragma unroll
      for (int r = 0; r < 4; r++) {
        const int ci = w * 16 + ks * 4 + r;
        float s = sD[ni][r];
        float f = 1.f + s + 0.5f * s * s;
        f = (cp <= ci) ? f : 0.f;
        sp[ci * 64 + (((cp >> 3) ^ (ci & 7)) * 8) + (cp & 7)] = (_Float16)f;
      }
    }
  }
  __syncthreads();
  // A-frag read of f + z_intra + AV MFMAs
  {
    f16x8 ff[2];
#pragma unroll
    for (int kk = 0; kk < 2; kk++) {
      ff[kk] = *(const f16x8*)&sp[crowA * 64 +
                                  (((kk * 4 + ks)) ^ (fr & 7)) * 8];
#pragma unroll
      for (int j = 0; j < 8; j++) zrow += (float)ff[kk][j];
    }
#pragma unroll
    for (int ni = 0; ni < 4; ni++)
#pragma unroll
      for (int kk = 0; kk < 2; kk++) {
        f16x8 fb = *(const f16x8*)&vt[(ni * 16 + fr) * 64 +
                                      (((kk * 4 + ks)) ^ (fr & 7)) * 8];
        acc[ni] = MFMAH(ff[kk], fb, acc[ni]);
      }
  }
  zrow += __shfl_xor(zrow, 16);
  zrow += __shfl_xor(zrow, 32);
  if (ks == 0) zinv[crowA] = 1.f / (zrow + EPSV);
  __syncthreads();

  // ---- epilogue
  const int crow = w * 16 + ks * 4;
#pragma unroll
  for (int ni = 0; ni < 4; ni++) {
    const int e = ni * 16 + fr;
#pragma unroll
    for (int r = 0; r < 4; r++) {
      float v = acc[ni][r] * zinv[crow + r];
      y[((size_t)bb * LL + nc * 64 + crow + r) * 1024 + h * 64 + e] =
          (_Float16)v;
    }
  }
}

// ---------------------------------------------------------------------------
extern "C" void kernel_launch(void* const* d_in, const int* in_sizes, int n_in,
                              void* d_out, int out_size, void* d_ws,
                              size_t ws_size, hipStream_t stream) {
  (void)in_sizes; (void)n_in; (void)out_size; (void)ws_size;
  const float* x  = (const float*)d_in[0];
  const float* Wq = (const float*)d_in[1];
  const float* Wk = (const float*)d_in[2];
  const float* Wv = (const float*)d_in[3];
  const float* Wo = (const float*)d_in[4];
  float* ws = (float*)d_ws;
  float* out = (float*)d_out;

  _Float16* vT = (_Float16*)(ws + OFF_VT);
  _Float16* y16 = (_Float16*)(ws + OFF_Y);
  // overlays in dead S region during projection
  _Float16* xf = (_Float16*)(ws + OFF_S);                  // 4096x1024
  _Float16* BT = xf + (size_t)4096 * 1024;                 // 1536x1024
  // overlay in dead Q region for output projection
  _Float16* WoT = (_Float16*)(ws + OFF_Q);                 // 1024x1024

  xcvt_kernel<<<2048, 256, 0, stream>>>(x, xf);
  tcvt_qkv_kernel<<<dim3(32, 48), 256, 0, stream>>>(Wq, Wk, Wv, BT);
  bgemm_kernel<0><<<dim3(24, 32), 256, 0, stream>>>(xf, BT, ws, vT);
  chunk_state_kernel<<<1024, 256, 0, stream>>>(ws, vT);
  scan_kernel<<<dim3(42, 32), 256, 0, stream>>>(ws);
  chunk_out_kernel<<<1024, 256, 0, stream>>>(ws, vT, y16);
  tcvt_wo_kernel<<<dim3(32, 32), 256, 0, stream>>>(Wo, WoT);
  bgemm_kernel<1><<<dim3(16, 32), 256, 0, stream>>>(y16, WoT, out, nullptr);
}

// Round 9
// 160.920 us; speedup vs baseline: 3.0661x; 1.0585x over previous
//
#include <hip/hip_runtime.h>

#define LL 2048
#define NH 16
#define DFEAT 273
#define SROW 280             // padded feature stride (f16 row of S / zk f32 row)
#define EPSV 1e-12f
#define INV_RRD 0.5f
#define INV_Q 0.17677669529663687f

// workspace layout (float offsets), total ~16.3M floats = 65 MB
#define OFF_Q   ((size_t)0)          // q fp32 [bh][l][16]
#define OFF_K   ((size_t)1048576)    // k fp32 [bh][l][16]
#define OFF_VT  ((size_t)2097152)    // vT f16 [bh][e][L]
#define OFF_S   ((size_t)4194304)    // S f16 [1024][64][SROW]; head hosts xf+BT overlays
// S size: 1024*64*280 f16 = 9,175,040 floats ; +64-float poison gap (finite-f16 pad
// for the t5=4 staging over-read; never written)
#define OFF_ZK  ((size_t)13369408)   // zk f32 [1024][SROW] = 286,720 floats
#define OFF_Y   ((size_t)13656128)   // y f16 [4096][1024] = 2,097,152 floats
#define OFF_WOT ((size_t)15753280)   // WoT f16 [1024][1024] = 524,288 floats

typedef __attribute__((ext_vector_type(8))) _Float16 f16x8;
typedef __attribute__((ext_vector_type(4))) float f32x4;

#define MFMAH(a, b, c) __builtin_amdgcn_mfma_f32_16x16x32_f16(a, b, c, 0, 0, 0)

__device__ __forceinline__ void llds16(const _Float16* g, _Float16* s) {
  __builtin_amdgcn_global_load_lds(
      (const __attribute__((address_space(1))) short*)(const short*)g,
      (__attribute__((address_space(3))) short*)(short*)s, 16, 0, 0);
}

// phi(row c of m)[d], fp32
__device__ __forceinline__ float featv(const float (*m)[17], int c, int d) {
  if (d == 0) return 1.f;
  if (d < 17) return m[c][d - 1] * INV_RRD;
  if (d < DFEAT) { int d2 = d - 17; return m[c][d2 >> 4] * m[c][d2 & 15] * INV_Q; }
  return 0.f;
}

// ---------------------------------------------------------------------------
// Fused prep: blocks [0,2048): x fp32 -> f16
//             blocks [2048,3584): transpose+cvt [Wq|Wk|Wv] -> BT[n][k]
//             blocks [3584,4608): transpose+cvt Wo -> WoT[n][k]
// ---------------------------------------------------------------------------
__global__ __launch_bounds__(256) void prep_kernel(
    const float* __restrict__ x, const float* __restrict__ Wq,
    const float* __restrict__ Wk, const float* __restrict__ Wv,
    const float* __restrict__ Wo, _Float16* __restrict__ xf,
    _Float16* __restrict__ BT, _Float16* __restrict__ WoT) {
  __shared__ float tile[32][33];
  const int bid = blockIdx.x;
  const int t = threadIdx.x;
  if (bid < 2048) {
    int i = (bid * 256 + t) * 8;
    float4 a = *(const float4*)&x[i];
    float4 b = *(const float4*)&x[i + 4];
    f16x8 o;
    o[0] = (_Float16)a.x; o[1] = (_Float16)a.y; o[2] = (_Float16)a.z;
    o[3] = (_Float16)a.w; o[4] = (_Float16)b.x; o[5] = (_Float16)b.y;
    o[6] = (_Float16)b.z; o[7] = (_Float16)b.w;
    *(f16x8*)&xf[i] = o;
    return;
  }
  const float* src;
  _Float16* dst;
  int ncol, c0, k0, n0;
  if (bid < 3584) {
    const int idx = bid - 2048;
    k0 = (idx & 31) * 32;
    n0 = (idx >> 5) * 32;
    if (n0 < 256)      { src = Wq; ncol = 256;  c0 = n0; }
    else if (n0 < 512) { src = Wk; ncol = 256;  c0 = n0 - 256; }
    else               { src = Wv; ncol = 1024; c0 = n0 - 512; }
    dst = BT;
  } else {
    const int idx = bid - 3584;
    k0 = (idx & 31) * 32;
    n0 = (idx >> 5) * 32;
    src = Wo; ncol = 1024; c0 = n0;
    dst = WoT;
  }
  {
    int kk = t >> 3, c4 = (t & 7) * 4;
    float4 v = *(const float4*)&src[(size_t)(k0 + kk) * ncol + c0 + c4];
    tile[kk][c4] = v.x; tile[kk][c4 + 1] = v.y;
    tile[kk][c4 + 2] = v.z; tile[kk][c4 + 3] = v.w;
  }
  __syncthreads();
  int cc = t >> 3, k4 = (t & 7) * 4;
  union { unsigned long long u; _Float16 f[4]; } p;
  p.f[0] = (_Float16)tile[k4 + 0][cc];
  p.f[1] = (_Float16)tile[k4 + 1][cc];
  p.f[2] = (_Float16)tile[k4 + 2][cc];
  p.f[3] = (_Float16)tile[k4 + 3][cc];
  *(unsigned long long*)&dst[(size_t)(n0 + cc) * 1024 + k0 + k4] = p.u;
}

// ---------------------------------------------------------------------------
// f16 MFMA GEMM, 128x64 tile, BK=64, double-buffered global_load_lds staging:
// { STAGE(next); COMPUTE(cur); __syncthreads(); }  — one barrier per K-step,
// staging latency hidden under the MFMA work.
// MODE 0: A=xf, B=BT(1536 rows) -> scatter q/k fp32 + vT f16.
// MODE 1: A=y,  B=WoT           -> fp32 out.
// ---------------------------------------------------------------------------
template <int MODE>
__global__ __launch_bounds__(256) void bgemm_kernel(
    const _Float16* __restrict__ A, const _Float16* __restrict__ B,
    float* __restrict__ dst, _Float16* __restrict__ vT) {
  __shared__ _Float16 lds[2][12288];  // per buf: A[0,8192) B[8192,12288)
  const int t = threadIdx.x;
  const int w = t >> 6, l = t & 63;
  const int m0 = blockIdx.y * 128, n0 = blockIdx.x * 64;
  const int rsub = l >> 3;
  const int g8 = ((l & 7) ^ rsub) * 8;
  const int fr = l & 15, ks = l >> 4;
  const int wr = w >> 1, wc = w & 1;

  f32x4 acc[4][2];
#pragma unroll
  for (int i = 0; i < 4; i++)
#pragma unroll
    for (int j = 0; j < 2; j++) acc[i][j] = (f32x4){0.f, 0.f, 0.f, 0.f};

  auto stage = [&](int buf, int k0) {
#pragma unroll
    for (int j = 0; j < 4; j++) {
      const int c = w * 4 + j;
      llds16(A + (size_t)(m0 + c * 8 + rsub) * 1024 + k0 + g8,
             &lds[buf][c * 512]);
    }
#pragma unroll
    for (int j = 0; j < 2; j++) {
      const int c = w * 2 + j;
      llds16(B + (size_t)(n0 + c * 8 + rsub) * 1024 + k0 + g8,
             &lds[buf][8192 + c * 512]);
    }
  };

  stage(0, 0);
  __syncthreads();
  for (int tt = 0; tt < 16; ++tt) {
    const int cur = tt & 1;
    if (tt < 15) stage(cur ^ 1, (tt + 1) * 64);
#pragma unroll
    for (int kk = 0; kk < 2; kk++) {
      const int so = ((kk * 4 + ks) ^ (fr & 7)) * 8;
      f16x8 fa[4], fb[2];
#pragma unroll
      for (int mi = 0; mi < 4; mi++)
        fa[mi] = *(const f16x8*)&lds[cur][(wr * 64 + mi * 16 + fr) * 64 + so];
#pragma unroll
      for (int ni = 0; ni < 2; ni++)
        fb[ni] =
            *(const f16x8*)&lds[cur][8192 + (wc * 32 + ni * 16 + fr) * 64 + so];
#pragma unroll
      for (int mi = 0; mi < 4; mi++)
#pragma unroll
        for (int ni = 0; ni < 2; ni++)
          acc[mi][ni] = MFMAH(fa[mi], fb[ni], acc[mi][ni]);
    }
    __syncthreads();
  }

  const int bb = m0 >> 11;
#pragma unroll
  for (int mi = 0; mi < 4; mi++) {
    const int lrow = (m0 & (LL - 1)) + wr * 64 + mi * 16 + ks * 4;
    const int grow = m0 + wr * 64 + mi * 16 + ks * 4;
#pragma unroll
    for (int ni = 0; ni < 2; ni++) {
      const int cn = n0 + wc * 32 + ni * 16 + fr;
      if (MODE == 1) {
#pragma unroll
        for (int r = 0; r < 4; r++)
          dst[(size_t)(grow + r) * 1024 + cn] = acc[mi][ni][r];
      } else if (cn < 256) {
        const int hq = cn >> 4, f = cn & 15;
#pragma unroll
        for (int r = 0; r < 4; r++)
          dst[OFF_Q + ((size_t)(bb * NH + hq) * LL + lrow + r) * 16 + f] =
              acc[mi][ni][r];
      } else if (cn < 512) {
        const int c2 = cn - 256, hq = c2 >> 4, f = c2 & 15;
#pragma unroll
        for (int r = 0; r < 4; r++)
          dst[OFF_K + ((size_t)(bb * NH + hq) * LL + lrow + r) * 16 + f] =
              acc[mi][ni][r];
      } else {
        const int c2 = cn - 512, hh = c2 >> 6, e = c2 & 63;
        union { unsigned long long u; _Float16 f[4]; } p;
#pragma unroll
        for (int r = 0; r < 4; r++) p.f[r] = (_Float16)acc[mi][ni][r];
        *(unsigned long long*)&vT[((size_t)(bb * NH + hh) * 64 + e) * LL +
                                  lrow] = p.u;
      }
    }
  }
}

// ---------------------------------------------------------------------------
// Per-chunk states: S[e][d] = sum_c kf[c][d] v[c][e] (f16 out), zk[d] sums.
// kf built per-lane directly in MFMA A-frag layout (no LDS build).
// ---------------------------------------------------------------------------
__global__ __launch_bounds__(256) void chunk_state_kernel(
    float* __restrict__ ws, const _Float16* __restrict__ vT) {
  __shared__ float kc[64][17];
  __shared__ _Float16 vt[4096];  // [64][64] swizzled
  const int t = threadIdx.x, blk = blockIdx.x;
  const int bh = blk >> 5, nc = blk & 31;
  const int w = t >> 6, l = t & 63;
  const int rsub = l >> 3, g8 = ((l & 7) ^ rsub) * 8;
  const int fr = l & 15, ks = l >> 4;

  {
    int c = t >> 2, u = (t & 3) * 4;
    float4 v =
        *(const float4*)&ws[OFF_K + ((size_t)bh * LL + nc * 64 + c) * 16 + u];
    kc[c][u] = v.x; kc[c][u + 1] = v.y; kc[c][u + 2] = v.z; kc[c][u + 3] = v.w;
  }
  const _Float16* vg = vT + (size_t)bh * 64 * LL + nc * 64;
#pragma unroll
  for (int j = 0; j < 2; j++) {
    const int c = w * 2 + j;
    llds16(vg + (size_t)(c * 8 + rsub) * LL + g8, &vt[c * 512]);
  }
  __syncthreads();

  _Float16* S16 = (_Float16*)(ws + OFF_S) + (size_t)blk * (64 * SROW);
  float* zk = ws + OFF_ZK + (size_t)blk * SROW;

  for (int t5 = 0; t5 < 5; t5++) {
    const int d0 = t5 * 64;
    const int d = d0 + w * 16 + fr;  // this lane's A-row (feature index)
    f16x8 af[2];
    float zpart = 0.f;
#pragma unroll
    for (int kk = 0; kk < 2; kk++)
#pragma unroll
      for (int j = 0; j < 8; j++) {
        float v = featv(kc, kk * 32 + ks * 8 + j, d);
        zpart += v;
        af[kk][j] = (_Float16)v;
      }
    zpart += __shfl_xor(zpart, 16);
    zpart += __shfl_xor(zpart, 32);
    if (ks == 0 && d < DFEAT) zk[d] = zpart;

    f32x4 sacc[4];
#pragma unroll
    for (int i = 0; i < 4; i++) sacc[i] = (f32x4){0.f, 0.f, 0.f, 0.f};
#pragma unroll
    for (int ni = 0; ni < 4; ni++)
#pragma unroll
      for (int kk = 0; kk < 2; kk++) {
        f16x8 fb = *(const f16x8*)&vt[(ni * 16 + fr) * 64 +
                                      (((kk * 4 + ks)) ^ (fr & 7)) * 8];
        sacc[ni] = MFMAH(af[kk], fb, sacc[ni]);
      }
    const int dstart = d0 + w * 16 + ks * 4;  // D-frag row base
    if (dstart < SROW) {
#pragma unroll
      for (int ni = 0; ni < 4; ni++) {
        union { unsigned long long u; _Float16 f[4]; } p;
#pragma unroll
        for (int r = 0; r < 4; r++)
          p.f[r] = (dstart + r < DFEAT) ? (_Float16)sacc[ni][r] : (_Float16)0.f;
        *(unsigned long long*)&S16[(size_t)(ni * 16 + fr) * SROW + dstart] =
            p.u;
      }
    }
  }
}

// ---------------------------------------------------------------------------
// Exclusive prefix over chunks: S (f16 pairs, f32 accum) and zk (f32).
// 4x unrolled with independent loads in flight (memory-level parallelism).
// ---------------------------------------------------------------------------
__global__ __launch_bounds__(256) void scan_kernel(float* __restrict__ ws) {
  const int bh = blockIdx.y;
  const int E = blockIdx.x * 256 + threadIdx.x;
  const int SU = 64 * SROW / 2;  // 8960 u32 per chunk-block
  if (E < SU) {
    unsigned int* base =
        (unsigned int*)((_Float16*)(ws + OFF_S) + (size_t)bh * 32 * (64 * SROW)) +
        E;
    float r0 = 0.f, r1 = 0.f;
    for (int nc = 0; nc < 32; nc += 4) {
      unsigned int av[4];
      av[0] = base[(size_t)(nc + 0) * SU];
      av[1] = base[(size_t)(nc + 1) * SU];
      av[2] = base[(size_t)(nc + 2) * SU];
      av[3] = base[(size_t)(nc + 3) * SU];
#pragma unroll
      for (int j = 0; j < 4; j++) {
        union { unsigned int u; _Float16 f[2]; } in, ov;
        in.u = av[j];
        ov.f[0] = (_Float16)r0; ov.f[1] = (_Float16)r1;
        base[(size_t)(nc + j) * SU] = ov.u;
        r0 += (float)in.f[0];
        r1 += (float)in.f[1];
      }
    }
  } else if (E < SU + SROW) {
    float* base = ws + OFF_ZK + (size_t)bh * 32 * SROW + (E - SU);
    float run = 0.f;
    for (int nc = 0; nc < 32; nc += 4) {
      float av[4];
      av[0] = base[(size_t)(nc + 0) * SROW];
      av[1] = base[(size_t)(nc + 1) * SROW];
      av[2] = base[(size_t)(nc + 2) * SROW];
      av[3] = base[(size_t)(nc + 3) * SROW];
#pragma unroll
      for (int j = 0; j < 4; j++) {
        base[(size_t)(nc + j) * SROW] = run;
        run += av[j];
      }
    }
  }
}

// ---------------------------------------------------------------------------
// Per-chunk output: y = (qf@Sp + tril(1+s+s^2/2)@V)/z -> y f16.
// Sp staging double-buffered: STAGE(next tile); COMPUTE(cur); barrier.
// ---------------------------------------------------------------------------
__global__ __launch_bounds__(256) void chunk_out_kernel(
    float* __restrict__ ws, const _Float16* __restrict__ vT,
    _Float16* __restrict__ y) {
  __shared__ float qc[64][17], kc[64][17];
  __shared__ _Float16 vt[4096];
  __shared__ _Float16 sp[2][4096];
  __shared__ float zpf[2][64];
  __shared__ float zinv[64];
  const int t = threadIdx.x, blk = blockIdx.x;
  const int bh = blk >> 5, nc = blk & 31;
  const int bb = bh >> 4, h = bh & 15;
  const int w = t >> 6, l = t & 63;
  const int rsub = l >> 3, g8 = ((l & 7) ^ rsub) * 8;
  const int fr = l & 15, ks = l >> 4;
  const int crowA = w * 16 + fr;  // A-frag row this lane holds

  {
    int c = t >> 2, u = (t & 3) * 4;
    float4 v =
        *(const float4*)&ws[OFF_Q + ((size_t)bh * LL + nc * 64 + c) * 16 + u];
    qc[c][u] = v.x; qc[c][u + 1] = v.y; qc[c][u + 2] = v.z; qc[c][u + 3] = v.w;
    float4 s =
        *(const float4*)&ws[OFF_K + ((size_t)bh * LL + nc * 64 + c) * 16 + u];
    kc[c][u] = s.x; kc[c][u + 1] = s.y; kc[c][u + 2] = s.z; kc[c][u + 3] = s.w;
  }
  const _Float16* vg = vT + (size_t)bh * 64 * LL + nc * 64;
#pragma unroll
  for (int j = 0; j < 2; j++) {
    const int c = w * 2 + j;
    llds16(vg + (size_t)(c * 8 + rsub) * LL + g8, &vt[c * 512]);
  }

  const _Float16* Sp16 =
      (const _Float16*)(ws + OFF_S) + (size_t)blk * (64 * SROW);
  const float* zp = ws + OFF_ZK + (size_t)blk * SROW;

  auto stage_sp = [&](int buf, int d0) {
#pragma unroll
    for (int j = 0; j < 2; j++) {
      const int c = w * 2 + j;
      llds16(Sp16 + (size_t)(c * 8 + rsub) * SROW + d0 + g8,
             &sp[buf][c * 512]);
    }
  };

  f32x4 acc[4];
#pragma unroll
  for (int i = 0; i < 4; i++) acc[i] = (f32x4){0.f, 0.f, 0.f, 0.f};
  float zrow = 0.f;

  stage_sp(0, 0);
  if (t < 64) zpf[0][t] = (t < DFEAT) ? zp[t] : 0.f;
  __syncthreads();

  // ---- inter: y += qf @ Sp (5 d-tiles of 64, double-buffered)
  for (int t5 = 0; t5 < 5; t5++) {
    const int d0 = t5 * 64;
    const int cur = t5 & 1;
    if (t5 < 4) {
      stage_sp(cur ^ 1, d0 + 64);
      if (t < 64)
        zpf[cur ^ 1][t] = (d0 + 64 + t < DFEAT) ? zp[d0 + 64 + t] : 0.f;
    }
    f16x8 af[2];
#pragma unroll
    for (int kk = 0; kk < 2; kk++)
#pragma unroll
      for (int j = 0; j < 8; j++) {
        const int dd = kk * 32 + ks * 8 + j;
        float v = featv(qc, crowA, d0 + dd);
        zrow = fmaf(v, zpf[cur][dd], zrow);
        af[kk][j] = (_Float16)v;
      }
#pragma unroll
    for (int ni = 0; ni < 4; ni++)
#pragma unroll
      for (int kk = 0; kk < 2; kk++) {
        f16x8 fb = *(const f16x8*)&sp[cur][(ni * 16 + fr) * 64 +
                                          (((kk * 4 + ks)) ^ (fr & 7)) * 8];
        acc[ni] = MFMAH(af[kk], fb, acc[ni]);
      }
    __syncthreads();
  }

  // ---- intra: s = (q.k)/4 via MFMA (K=32, upper half zero)
  {
    float qreg[16];
#pragma unroll
    for (int i = 0; i < 16; i++) qreg[i] = qc[crowA][i];
    f16x8 aq;
#pragma unroll
    for (int j = 0; j < 8; j++)
      aq[j] = (ks < 2) ? (_Float16)(0.25f * qreg[(ks * 8 + j) & 15])
                       : (_Float16)0.f;
    const f32x4 zero4 = {0.f, 0.f, 0.f, 0.f};
    f32x4 sD[4];
#pragma unroll
    for (int ni = 0; ni < 4; ni++) {
      f16x8 bk;
#pragma unroll
      for (int j = 0; j < 8; j++)
        bk[j] = (ks < 2) ? (_Float16)kc[ni * 16 + fr][(ks * 8 + j) & 15]
                         : (_Float16)0.f;
      sD[ni] = MFMAH(aq, bk, zero4);
    }
    // f = tril(1 + s + s^2/2) -> write into sp[0] (swizzled) for A-frag reads
#pragma unroll
    for (int ni = 0; ni < 4; ni++) {
      const int cp = ni * 16 + fr;
#pragma unroll
      for (int r = 0; r < 4; r++) {
        const int ci = w * 16 + ks * 4 + r;
        float s = sD[ni][r];
        float f = 1.f + s + 0.5f * s * s;
        f = (cp <= ci) ? f : 0.f;
        sp[0][ci * 64 + (((cp >> 3) ^ (ci & 7)) * 8) + (cp & 7)] = (_Float16)f;
      }
    }
  }
  __syncthreads();
  // A-frag read of f + z_intra + AV MFMAs
  {
    f16x8 ff[2];
#pragma unroll
    for (int kk = 0; kk < 2; kk++) {
      ff[kk] = *(const f16x8*)&sp[0][crowA * 64 +
                                     (((kk * 4 + ks)) ^ (fr & 7)) * 8];
#pragma unroll
      for (int j = 0; j < 8; j++) zrow += (float)ff[kk][j];
    }
#pragma unroll
    for (int ni = 0; ni < 4; ni++)
#pragma unroll
      for (int kk = 0; kk < 2; kk++) {
        f16x8 fb = *(const f16x8*)&vt[(ni * 16 + fr) * 64 +
                                      (((kk * 4 + ks)) ^ (fr & 7)) * 8];
        acc[ni] = MFMAH(ff[kk], fb, acc[ni]);
      }
  }
  zrow += __shfl_xor(zrow, 16);
  zrow += __shfl_xor(zrow, 32);
  if (ks == 0) zinv[crowA] = 1.f / (zrow + EPSV);
  __syncthreads();

  // ---- epilogue
  const int crow = w * 16 + ks * 4;
#pragma unroll
  for (int ni = 0; ni < 4; ni++) {
    const int e = ni * 16 + fr;
#pragma unroll
    for (int r = 0; r < 4; r++) {
      float v = acc[ni][r] * zinv[crow + r];
      y[((size_t)bb * LL + nc * 64 + crow + r) * 1024 + h * 64 + e] =
          (_Float16)v;
    }
  }
}

// ---------------------------------------------------------------------------
extern "C" void kernel_launch(void* const* d_in, const int* in_sizes, int n_in,
                              void* d_out, int out_size, void* d_ws,
                              size_t ws_size, hipStream_t stream) {
  (void)in_sizes; (void)n_in; (void)out_size; (void)ws_size;
  const float* x  = (const float*)d_in[0];
  const float* Wq = (const float*)d_in[1];
  const float* Wk = (const float*)d_in[2];
  const float* Wv = (const float*)d_in[3];
  const float* Wo = (const float*)d_in[4];
  float* ws = (float*)d_ws;
  float* out = (float*)d_out;

  _Float16* vT = (_Float16*)(ws + OFF_VT);
  _Float16* y16 = (_Float16*)(ws + OFF_Y);
  _Float16* WoT = (_Float16*)(ws + OFF_WOT);
  // overlays in dead S region during projection
  _Float16* xf = (_Float16*)(ws + OFF_S);                  // 4096x1024
  _Float16* BT = xf + (size_t)4096 * 1024;                 // 1536x1024

  prep_kernel<<<4608, 256, 0, stream>>>(x, Wq, Wk, Wv, Wo, xf, BT, WoT);
  bgemm_kernel<0><<<dim3(24, 32), 256, 0, stream>>>(xf, BT, ws, vT);
  chunk_state_kernel<<<1024, 256, 0, stream>>>(ws, vT);
  scan_kernel<<<dim3(37, 32), 256, 0, stream>>>(ws);
  chunk_out_kernel<<<1024, 256, 0, stream>>>(ws, vT, y16);
  bgemm_kernel<1><<<dim3(16, 32), 256, 0, stream>>>(y16, WoT, out, nullptr);
}